// Round 9
// baseline (1161.564 us; speedup 1.0000x reference)
//
#include <hip/hip_runtime.h>

#define NNODES 100000
#define NEDGES 1600000
#define NGRAPHS 2048
#define BN_EPS 1e-5f

typedef __attribute__((ext_vector_type(8))) short bf16x8;
typedef __attribute__((ext_vector_type(4))) float f32x4;

// RNE float -> bf16 (as short bits)
__device__ __forceinline__ short f2bf(float x) {
    unsigned u = __float_as_uint(x);
    unsigned r = u + 0x7FFF + ((u >> 16) & 1);
    return (short)(r >> 16);
}
__device__ __forceinline__ float bf2f(short h) {
    return __uint_as_float(((unsigned)(unsigned short)h) << 16);
}

// ---------------- CSR build ----------------
// Single atomic pass with line-padded counters; fill pass atomic-free.
__global__ __launch_bounds__(256) void degoff_kernel(const int* __restrict__ dstA,
                                                     int* __restrict__ degp,
                                                     int* __restrict__ off) {
    int e = blockIdx.x * 256 + threadIdx.x;
    if (e < NEDGES) {
        int d = dstA[e];
        int c = atomicAdd(&degp[d << 4], 1);  // padded: 1 counter per 64B line
        off[e] = (d << 8) | c;                // max deg ~35 << 256 for uniform-random edges
    }
}

__global__ __launch_bounds__(256) void scan1_kernel(const int* __restrict__ degp,
                                                    int* __restrict__ partials) {
    int b = blockIdx.x;
    int i = b * 256 + threadIdx.x;
    int v = (i < NNODES) ? degp[i << 4] : 0;
    __shared__ int wsum[4];
#pragma unroll
    for (int off = 32; off; off >>= 1) v += __shfl_down(v, off);
    if ((threadIdx.x & 63) == 0) wsum[threadIdx.x >> 6] = v;
    __syncthreads();
    if (threadIdx.x == 0) partials[b] = wsum[0] + wsum[1] + wsum[2] + wsum[3];
}

__global__ __launch_bounds__(512) void scan2_kernel(int* __restrict__ partials, int nb) {
    __shared__ int s[512];
    int t = threadIdx.x;
    int v = (t < nb) ? partials[t] : 0;
    s[t] = v;
    __syncthreads();
    for (int off = 1; off < 512; off <<= 1) {
        int u = (t >= off) ? s[t - off] : 0;
        __syncthreads();
        s[t] += u;
        __syncthreads();
    }
    if (t < nb) partials[t] = s[t] - v;  // exclusive
}

__global__ __launch_bounds__(256) void scan3_kernel(const int* __restrict__ degp,
                                                    const int* __restrict__ partials,
                                                    int* __restrict__ rowptr,
                                                    const int* __restrict__ batch,
                                                    int* __restrict__ gstart) {
    int b = blockIdx.x;
    int t = threadIdx.x;
    int i = b * 256 + t;
    __shared__ int s[256];
    int v = (i < NNODES) ? degp[i << 4] : 0;
    s[t] = v;
    __syncthreads();
    for (int off = 1; off < 256; off <<= 1) {
        int u = (t >= off) ? s[t - off] : 0;
        __syncthreads();
        s[t] += u;
        __syncthreads();
    }
    if (i < NNODES) {
        int ex = partials[b] + s[t] - v;
        rowptr[i] = ex;
        int bb = batch[i];
        int bp = (i == 0) ? -1 : batch[i - 1];
        for (int g = bp + 1; g <= bb; ++g) gstart[g] = i;
        if (i == NNODES - 1)
            for (int g = bb + 1; g <= NGRAPHS; ++g) gstart[g] = NNODES;
    }
    if (b == 0 && t == 0) rowptr[NNODES] = NEDGES;
}

__global__ __launch_bounds__(256) void fill2_kernel(const int* __restrict__ srcA,
                                                    const int* __restrict__ rowptr,
                                                    const int* __restrict__ off,
                                                    int* __restrict__ adj) {
    int e = blockIdx.x * 256 + threadIdx.x;
    if (e < NEDGES) {
        int v = off[e];
        adj[rowptr[v >> 8] + (v & 255)] = srcA[e];  // no atomic; rowptr is L2-resident
    }
}

// ---- pad x (NNODES x 66 fp32) into stride-68 rows so the L0 gather can use 16B
// requests (R7 evidence: gathers are request-rate bound). Exact copy + zeros.
__global__ __launch_bounds__(256) void pad66_kernel(const float* __restrict__ x,
                                                    float* __restrict__ xpad) {
    int idx = blockIdx.x * 256 + threadIdx.x;
    if (idx >= NNODES * 17) return;
    int node = idx / 17;
    int c = idx - node * 17;
    float4 v;
    if (c < 16) {
        float2 a = *(const float2*)&x[(size_t)node * 66 + c * 4];
        float2 b = *(const float2*)&x[(size_t)node * 66 + c * 4 + 2];
        v = make_float4(a.x, a.y, b.x, b.y);
    } else {
        float2 a = *(const float2*)&x[(size_t)node * 66 + 64];
        v = make_float4(a.x, a.y, 0.f, 0.f);
    }
    *(float4*)&xpad[(size_t)node * 68 + c * 4] = v;
}

// ------- gather aggregation: agg[n] = x[n] + sum_{s in adj[n]} x[s] (+bias) -------
// Fabric-ceiling bound (~6.6 TB/s logical). Unroll 8 => 8 outstanding row loads/thread.
// SPLIT epilogue emits hi/lo bf16 planes for the ASPLIT GEMM consumer.
template <int DIM, int CHUNK, int OSTRIDE, bool SPLIT>
__global__ __launch_bounds__(256) void gather_kernel(const float* __restrict__ x,
                                                     const int* __restrict__ rowptr,
                                                     const int* __restrict__ adj,
                                                     float* __restrict__ agg,
                                                     short* __restrict__ oh,
                                                     short* __restrict__ ol,
                                                     const float* __restrict__ bias) {
    constexpr int PE = DIM / CHUNK;
    constexpr int PEL = SPLIT ? (OSTRIDE / CHUNK) : PE;
    int gid = blockIdx.x * 256 + threadIdx.x;
    if (gid >= NNODES * PEL) return;
    int node = gid / PEL;
    int c = gid - node * PEL;
    if constexpr (SPLIT) {
        if (c >= PE) {  // zero-pad columns [DIM, OSTRIDE)
            size_t o = (size_t)node * OSTRIDE + c * CHUNK;
            if constexpr (CHUNK == 4) {
                short4 z;
                z.x = z.y = z.z = z.w = 0;
                *(short4*)&oh[o] = z;
                *(short4*)&ol[o] = z;
            } else {
                short2 z;
                z.x = z.y = 0;
                *(short2*)&oh[o] = z;
                *(short2*)&ol[o] = z;
            }
            return;
        }
    }
    const int beg = rowptr[node];
    const int end = rowptr[node + 1];
    if constexpr (CHUNK == 4) {
        const float4* xp = (const float4*)x;
        float4 acc = xp[(size_t)node * PE + c];
        float4 acc1 = make_float4(0.f, 0.f, 0.f, 0.f);
        int i = beg;
        for (; i + 8 <= end; i += 8) {
            int s0 = adj[i + 0], s1 = adj[i + 1], s2 = adj[i + 2], s3 = adj[i + 3];
            int s4 = adj[i + 4], s5 = adj[i + 5], s6 = adj[i + 6], s7 = adj[i + 7];
            float4 v0 = xp[(size_t)s0 * PE + c];
            float4 v1 = xp[(size_t)s1 * PE + c];
            float4 v2 = xp[(size_t)s2 * PE + c];
            float4 v3 = xp[(size_t)s3 * PE + c];
            float4 v4 = xp[(size_t)s4 * PE + c];
            float4 v5 = xp[(size_t)s5 * PE + c];
            float4 v6 = xp[(size_t)s6 * PE + c];
            float4 v7 = xp[(size_t)s7 * PE + c];
            acc.x += v0.x + v1.x; acc.y += v0.y + v1.y; acc.z += v0.z + v1.z; acc.w += v0.w + v1.w;
            acc1.x += v2.x + v3.x; acc1.y += v2.y + v3.y; acc1.z += v2.z + v3.z; acc1.w += v2.w + v3.w;
            acc.x += v4.x + v5.x; acc.y += v4.y + v5.y; acc.z += v4.z + v5.z; acc.w += v4.w + v5.w;
            acc1.x += v6.x + v7.x; acc1.y += v6.y + v7.y; acc1.z += v6.z + v7.z; acc1.w += v6.w + v7.w;
        }
        for (; i + 4 <= end; i += 4) {
            int s0 = adj[i + 0], s1 = adj[i + 1], s2 = adj[i + 2], s3 = adj[i + 3];
            float4 v0 = xp[(size_t)s0 * PE + c];
            float4 v1 = xp[(size_t)s1 * PE + c];
            float4 v2 = xp[(size_t)s2 * PE + c];
            float4 v3 = xp[(size_t)s3 * PE + c];
            acc.x += v0.x + v1.x; acc.y += v0.y + v1.y; acc.z += v0.z + v1.z; acc.w += v0.w + v1.w;
            acc1.x += v2.x + v3.x; acc1.y += v2.y + v3.y; acc1.z += v2.z + v3.z; acc1.w += v2.w + v3.w;
        }
        for (; i < end; ++i) {
            int s = adj[i];
            float4 v = xp[(size_t)s * PE + c];
            acc.x += v.x; acc.y += v.y; acc.z += v.z; acc.w += v.w;
        }
        acc.x += acc1.x; acc.y += acc1.y; acc.z += acc1.z; acc.w += acc1.w;
        if (bias) {
            float4 b = *(const float4*)&bias[c * 4];
            acc.x += b.x; acc.y += b.y; acc.z += b.z; acc.w += b.w;
        }
        if constexpr (SPLIT) {
            size_t o = (size_t)node * OSTRIDE + c * 4;
            short4 h4, l4;
            h4.x = f2bf(acc.x); l4.x = f2bf(acc.x - bf2f(h4.x));
            h4.y = f2bf(acc.y); l4.y = f2bf(acc.y - bf2f(h4.y));
            h4.z = f2bf(acc.z); l4.z = f2bf(acc.z - bf2f(h4.z));
            h4.w = f2bf(acc.w); l4.w = f2bf(acc.w - bf2f(h4.w));
            *(short4*)&oh[o] = h4;
            *(short4*)&ol[o] = l4;
        } else {
            *(float4*)&agg[(size_t)node * OSTRIDE + c * 4] = acc;
        }
    } else {
        const float2* xp = (const float2*)x;
        float2 acc = xp[(size_t)node * PE + c];
        float2 acc1 = make_float2(0.f, 0.f);
        int i = beg;
        for (; i + 8 <= end; i += 8) {
            int s0 = adj[i + 0], s1 = adj[i + 1], s2 = adj[i + 2], s3 = adj[i + 3];
            int s4 = adj[i + 4], s5 = adj[i + 5], s6 = adj[i + 6], s7 = adj[i + 7];
            float2 v0 = xp[(size_t)s0 * PE + c];
            float2 v1 = xp[(size_t)s1 * PE + c];
            float2 v2 = xp[(size_t)s2 * PE + c];
            float2 v3 = xp[(size_t)s3 * PE + c];
            float2 v4 = xp[(size_t)s4 * PE + c];
            float2 v5 = xp[(size_t)s5 * PE + c];
            float2 v6 = xp[(size_t)s6 * PE + c];
            float2 v7 = xp[(size_t)s7 * PE + c];
            acc.x += v0.x + v1.x; acc.y += v0.y + v1.y;
            acc1.x += v2.x + v3.x; acc1.y += v2.y + v3.y;
            acc.x += v4.x + v5.x; acc.y += v4.y + v5.y;
            acc1.x += v6.x + v7.x; acc1.y += v6.y + v7.y;
        }
        for (; i + 4 <= end; i += 4) {
            int s0 = adj[i + 0], s1 = adj[i + 1], s2 = adj[i + 2], s3 = adj[i + 3];
            float2 v0 = xp[(size_t)s0 * PE + c];
            float2 v1 = xp[(size_t)s1 * PE + c];
            float2 v2 = xp[(size_t)s2 * PE + c];
            float2 v3 = xp[(size_t)s3 * PE + c];
            acc.x += v0.x + v1.x; acc.y += v0.y + v1.y;
            acc1.x += v2.x + v3.x; acc1.y += v2.y + v3.y;
        }
        for (; i < end; ++i) {
            int s = adj[i];
            float2 v = xp[(size_t)s * PE + c];
            acc.x += v.x; acc.y += v.y;
        }
        acc.x += acc1.x; acc.y += acc1.y;
        if constexpr (SPLIT) {
            size_t o = (size_t)node * OSTRIDE + c * 2;
            short2 h2, l2;
            h2.x = f2bf(acc.x); l2.x = f2bf(acc.x - bf2f(h2.x));
            h2.y = f2bf(acc.y); l2.y = f2bf(acc.y - bf2f(h2.y));
            *(short2*)&oh[o] = h2;
            *(short2*)&ol[o] = l2;
        } else {
            *(float2*)&agg[(size_t)node * OSTRIDE + c * 2] = acc;
        }
    }
}

// ---------------- BN stats (standalone, used once for L2) ----------------
template <int N>
__global__ __launch_bounds__(256) void bnstats_kernel(const float* __restrict__ h,
                                                      float* __restrict__ sums) {
    constexpr int SHIFT = (N == 128) ? 7 : 8;
    int t = blockIdx.x * 256 + threadIdx.x;
    int col = t & (N - 1);
    int slice = t >> SHIFT;
    int stride = (gridDim.x * 256) >> SHIFT;
    float s = 0.f, s2 = 0.f;
    for (int r = slice; r < NNODES; r += stride) {
        float v = h[(size_t)r * N + col];
        s += v;
        s2 += v * v;
    }
    atomicAdd(&sums[col], s);
    atomicAdd(&sums[256 + col], s2);
}

// ---- W pre-pass (ALL weights in ONE dispatch): decompose W into hi/lo bf16 B-frags ----
// B-frag layout (mfma_f32_16x16x32_bf16): lane holds n=lane&15, k=(lane>>4)*8+j.
// Buffer index: ((nt*KT + kt)*64 + lane)*8 + j.
struct WDesc {
    const float* W;
    int Kw, N, KT, hioff, looff;
};
struct WDescs {
    WDesc d[8];
    int cum[9];
};
__global__ __launch_bounds__(256) void wprep_all_kernel(WDescs wd, short* __restrict__ wf) {
    int idx = blockIdx.x * 256 + threadIdx.x;
    if (idx >= wd.cum[8]) return;
    int s = 0;
#pragma unroll
    for (int i = 1; i < 8; ++i) s += (idx >= wd.cum[i]);
    int r = idx - wd.cum[s];
    const WDesc D = wd.d[s];
    int j = r & 7;
    int lane = (r >> 3) & 63;
    int t = r >> 9;  // nt*KT + kt
    int kt = t % D.KT;
    int nt = t / D.KT;
    int k = kt * 32 + ((lane >> 4) << 3) + j;
    int n = (nt << 4) + (lane & 15);
    float w = (k < D.Kw) ? D.W[(size_t)k * D.N + n] : 0.f;
    short hi = f2bf(w);
    wf[D.hioff + r] = hi;
    wf[D.looff + r] = f2bf(w - bf2f(hi));
}

// ---------------- split-bf16 MFMA GEMM: C = op(A) @ W + bias ----------------
// LDS-free main loop. Block = 4 waves; BM = 64*MROWS; NT N-tiles (grid.y splits N).
// MROWS=2 everywhere (R6/R7 verified; R8's MROWS=3/MINW=2 regressed — occupancy fell
// to 2 waves/SIMD). R9: BN finalize INLINED — each BN block computes scale/shift from
// raw stats (same fp32 ops as the old bnfinal => bit-identical) into the shared sbuf,
// dropping 3 one-block bnfinal dispatches. FUSE_STATS and BNRELU_A never co-occur,
// so sbuf is shared. Simple codegen retained (R5 spill lesson: no register queues).
template <int NT, int KTLOOP, int KTT, int MROWS, bool BNRELU_A, bool RELU_OUT, bool FUSE_STATS,
          bool SPLITK, bool ASPLIT, bool SPLIT_OUT, int MINW>
__global__ __launch_bounds__(256, MINW) void gemm_mfma_kernel(
    const float* __restrict__ A, const short* __restrict__ Ah, const short* __restrict__ Al,
    const short* __restrict__ whi, const short* __restrict__ wlo, const float* __restrict__ bias,
    const float* __restrict__ gamma, const float* __restrict__ beta, float* __restrict__ C,
    short* __restrict__ Ch, short* __restrict__ Cl, float* __restrict__ stats, int M, int Kst,
    int N) {
    static_assert(!(FUSE_STATS && BNRELU_A), "sbuf is shared between the two roles");
    __shared__ float sbuf[512];
    const int tid = threadIdx.x;
    const int wave = tid >> 6;
    const int lane = tid & 63;
    const int quad = lane >> 4;
    const int l16 = lane & 15;
    const int mrow = blockIdx.x * (64 * MROWS) + wave * 16 + l16;
    const int ngrp = blockIdx.y * NT * 16;
    const size_t wgrp = (size_t)blockIdx.y * NT * KTT * 512;
    const int ktbeg = SPLITK ? blockIdx.z * KTLOOP : 0;
    float* Cb = SPLITK ? C + (size_t)blockIdx.z * M * N : C;

    if (FUSE_STATS) {
        sbuf[tid] = 0.f;
        sbuf[tid + 256] = 0.f;
        __syncthreads();
    }
    if (BNRELU_A) {
        // Inline bnfinal: stats -> scale@sbuf[c] / shift@sbuf[256+c]. Same fp32 formula
        // as the old bnfinal kernel => bit-identical sc/sh.
        if (tid < Kst) {
            const float invM = 1.0f / NNODES;
            float mean = stats[tid] * invM;
            float var = stats[256 + tid] * invM - mean * mean;
            float sc = gamma[tid] * rsqrtf(var + BN_EPS);
            sbuf[tid] = sc;
            sbuf[256 + tid] = beta[tid] - mean * sc;
        }
        __syncthreads();
    }

    f32x4 acc[MROWS][NT] = {};

    auto kstep = [&](int kt) {
        const int kq = kt * 32 + quad * 8;
        bf16x8 ahi[MROWS], alo[MROWS];
        if constexpr (ASPLIT) {
#pragma unroll
            for (int m = 0; m < MROWS; ++m) {
                const size_t ro = (size_t)(mrow + m * 64) * Kst + kq;
                ahi[m] = *(const bf16x8*)(Ah + ro);
                alo[m] = *(const bf16x8*)(Al + ro);
            }
        } else {
            float sc[8], sh[8];
            if constexpr (BNRELU_A) {
                float4 sc0 = *(const float4*)&sbuf[kq];
                float4 sc1 = *(const float4*)&sbuf[kq + 4];
                float4 sh0 = *(const float4*)&sbuf[256 + kq];
                float4 sh1 = *(const float4*)&sbuf[256 + kq + 4];
                sc[0] = sc0.x; sc[1] = sc0.y; sc[2] = sc0.z; sc[3] = sc0.w;
                sc[4] = sc1.x; sc[5] = sc1.y; sc[6] = sc1.z; sc[7] = sc1.w;
                sh[0] = sh0.x; sh[1] = sh0.y; sh[2] = sh0.z; sh[3] = sh0.w;
                sh[4] = sh1.x; sh[5] = sh1.y; sh[6] = sh1.z; sh[7] = sh1.w;
            }
#pragma unroll
            for (int m = 0; m < MROWS; ++m) {
                const float* ap = A + (size_t)(mrow + m * 64) * Kst + kq;
                float4 x0 = *(const float4*)ap;
                float4 x1 = *(const float4*)(ap + 4);
                float a8[8] = {x0.x, x0.y, x0.z, x0.w, x1.x, x1.y, x1.z, x1.w};
                if constexpr (BNRELU_A) {
#pragma unroll
                    for (int i = 0; i < 8; ++i) a8[i] = fmaxf(a8[i] * sc[i] + sh[i], 0.f);
                }
#pragma unroll
                for (int i = 0; i < 8; ++i) {
                    short h = f2bf(a8[i]);
                    ahi[m][i] = h;
                    alo[m][i] = f2bf(a8[i] - bf2f(h));
                }
            }
        }
#pragma unroll
        for (int nt = 0; nt < NT; ++nt) {
            const size_t boff = wgrp + (((size_t)nt * KTT + kt) << 9) + ((size_t)lane << 3);
            bf16x8 bh = *(const bf16x8*)(whi + boff);
            bf16x8 bl = *(const bf16x8*)(wlo + boff);
#pragma unroll
            for (int m = 0; m < MROWS; ++m) {
                acc[m][nt] = __builtin_amdgcn_mfma_f32_16x16x32_bf16(ahi[m], bh, acc[m][nt], 0, 0, 0);
                acc[m][nt] = __builtin_amdgcn_mfma_f32_16x16x32_bf16(alo[m], bh, acc[m][nt], 0, 0, 0);
                acc[m][nt] = __builtin_amdgcn_mfma_f32_16x16x32_bf16(ahi[m], bl, acc[m][nt], 0, 0, 0);
                acc[m][nt] = __builtin_amdgcn_mfma_f32_16x16x32_bf16(alo[m], bl, acc[m][nt], 0, 0, 0);
            }
        }
    };

    if constexpr (ASPLIT) {
#pragma unroll 2
        for (int k = 0; k < KTLOOP; ++k) kstep(ktbeg + k);
    } else {
#pragma unroll 1
        for (int k = 0; k < KTLOOP; ++k) kstep(ktbeg + k);
    }

    // Epilogue. C/D frag: col = l16 (+16*nt), row = quad*4 + reg (m89-verified).
#pragma unroll
    for (int m = 0; m < MROWS; ++m) {
        const int mbase = blockIdx.x * (64 * MROWS) + m * 64 + wave * 16 + quad * 4;
#pragma unroll
        for (int nt = 0; nt < NT; ++nt) {
            int gn = ngrp + nt * 16 + l16;
            float bv = bias ? bias[gn] : 0.f;
            float s = 0.f, s2 = 0.f;
#pragma unroll
            for (int r = 0; r < 4; ++r) {
                int gm = mbase + r;
                float v = acc[m][nt][r] + bv;
                if (RELU_OUT) v = fmaxf(v, 0.f);
                if (gm < M) {
                    if constexpr (SPLIT_OUT) {
                        short h = f2bf(v);
                        Ch[(size_t)gm * N + gn] = h;
                        Cl[(size_t)gm * N + gn] = f2bf(v - bf2f(h));
                    } else {
                        Cb[(size_t)gm * N + gn] = v;
                    }
                    if (FUSE_STATS) {
                        s += v;
                        s2 += v * v;
                    }
                }
            }
            if (FUSE_STATS) {
                s += __shfl_xor(s, 16);
                s += __shfl_xor(s, 32);
                s2 += __shfl_xor(s2, 16);
                s2 += __shfl_xor(s2, 32);
                if (quad == 0) {
                    atomicAdd(&sbuf[gn], s);
                    atomicAdd(&sbuf[256 + gn], s2);
                }
            }
        }
    }
    if (FUSE_STATS) {
        __syncthreads();
        if (tid < N) {
            atomicAdd(&stats[tid], sbuf[tid]);
            atomicAdd(&stats[256 + tid], sbuf[256 + tid]);
        }
    }
}

// ---- reduce 8 split-K partials + bias -> out (fc1: M=2048,N=128) ----
__global__ __launch_bounds__(256) void splitk_reduce_kernel(const float* __restrict__ part,
                                                            const float* __restrict__ bias,
                                                            float* __restrict__ out) {
    const int i4 = blockIdx.x * 256 + threadIdx.x;
    const int TOT4 = NGRAPHS * 128 / 4;  // 65536
    if (i4 >= TOT4) return;
    const float4* p = (const float4*)part;
    float4 acc = make_float4(0.f, 0.f, 0.f, 0.f);
#pragma unroll
    for (int c = 0; c < 8; ++c) {
        float4 v = p[(size_t)c * TOT4 + i4];
        acc.x += v.x;
        acc.y += v.y;
        acc.z += v.z;
        acc.w += v.w;
    }
    float4 b = ((const float4*)bias)[i4 & 31];
    acc.x += b.x;
    acc.y += b.y;
    acc.z += b.z;
    acc.w += b.w;
    ((float4*)out)[i4] = acc;
}

// ---- segmented pool over sorted batch; SPLIT emits hi/lo planes for fc0 ----
template <bool SPLIT>
__global__ __launch_bounds__(128) void pool_seg_kernel(const float* __restrict__ h,
                                                       const int* __restrict__ gstart,
                                                       float* __restrict__ g,
                                                       short* __restrict__ oh,
                                                       short* __restrict__ ol) {
    int gr = blockIdx.x;
    int t = threadIdx.x;
    int beg = gstart[gr];
    int end = gstart[gr + 1];
    float acc = 0.f;
    for (int r = beg; r < end; ++r) acc += h[(size_t)r * 128 + t];
    if constexpr (SPLIT) {
        short hh = f2bf(acc);
        oh[(size_t)gr * 128 + t] = hh;
        ol[(size_t)gr * 128 + t] = f2bf(acc - bf2f(hh));
    } else {
        g[(size_t)gr * 128 + t] = acc;
    }
}

extern "C" void kernel_launch(void* const* d_in, const int* in_sizes, int n_in, void* d_out,
                              int out_size, void* d_ws, size_t ws_size, hipStream_t stream) {
    const float* x = (const float*)d_in[0];
    const int* ei = (const int*)d_in[1];
    const int* batch = (const int*)d_in[2];
    const int* srcA = ei;
    const int* dstA = ei + NEDGES;

    const float* g0_w1 = (const float*)d_in[3];
    const float* g0_b1 = (const float*)d_in[4];
    const float* g0_ga = (const float*)d_in[5];
    const float* g0_be = (const float*)d_in[6];
    const float* g0_w2 = (const float*)d_in[7];
    const float* g0_b2 = (const float*)d_in[8];
    const float* g1_w1 = (const float*)d_in[9];
    const float* g1_b1 = (const float*)d_in[10];
    const float* g1_ga = (const float*)d_in[11];
    const float* g1_be = (const float*)d_in[12];
    const float* g1_w2 = (const float*)d_in[13];
    const float* g1_b2 = (const float*)d_in[14];
    const float* g2_w1 = (const float*)d_in[15];
    const float* g2_b1 = (const float*)d_in[16];
    const float* g2_ga = (const float*)d_in[17];
    const float* g2_be = (const float*)d_in[18];
    const float* g2_w2 = (const float*)d_in[19];
    const float* g2_b2 = (const float*)d_in[20];
    const float* fc0_w = (const float*)d_in[21];
    const float* fc0_b = (const float*)d_in[22];
    const float* fc1_w = (const float*)d_in[23];
    const float* fc1_b = (const float*)d_in[24];

    // --- workspace layout ---
    float* ws = (float*)d_ws;
    const size_t BUF = (size_t)NNODES * 256;
    float* R0 = ws;
    float* R1 = R0 + BUF;  // also fc1 split-K partial buffer (8*2048*128 floats)
    float* stats0 = R1 + BUF;                           // 512 (L0 BN raw stats)
    float* stats1 = stats0 + 512;                       // 512 (L1)
    float* stats2 = stats1 + 512;                       // 512 (L2, via bnstats)
    float* g = stats2 + 512;                            // 2048*128 pooled
    float* gh = g + (size_t)NGRAPHS * 128;              // 2048*1024 fc hidden
    int* rowptr = (int*)(gh + (size_t)NGRAPHS * 1024);  // NNODES+1
    int* adj = rowptr + NNODES + 4;                     // NEDGES
    int* partials = adj + NEDGES;                       // 391
    int* gstart = partials + 512;                       // NGRAPHS+1
    short* wf = (short*)(gstart + 2052);                // W-fragment arena

    // CSR scratch overlays dead R0 (R0 first written by L0 gather, after fill2):
    int* degp = (int*)R0;           // NNODES*16 ints (padded counters, 1/line)
    int* off = degp + NNODES * 16;  // NEDGES packed (dst<<8)|slot
    // Padded-x overlay in R1 (dead until L0a writes R1; gather reads it before that):
    float* xpad = R1;  // NNODES*68 floats (~27 MB)

    short* whi[8];
    short* wlo[8];
    for (int i = 0; i < 6; ++i) {
        whi[i] = wf + (size_t)i * 131072;
        wlo[i] = whi[i] + 65536;
    }
    whi[6] = wf + 6 * 131072;
    wlo[6] = whi[6] + 131072;
    whi[7] = whi[6] + 262144;
    wlo[7] = whi[7] + 131072;

    // bf16 A-plane overlays (hi plane then lo plane, both stride = padded K):
    short* P0h = (short*)R0;  // L0 gather out, stride 96 (cols 66..95 zeroed)
    short* P0l = P0h + (size_t)NNODES * 96;
    short* P1h = (short*)R1;  // L1 gather out, stride 128
    short* P1l = P1h + (size_t)NNODES * 128;
    short* P2h = (short*)R1;  // L1b out, stride 256 (fills R1 exactly)
    short* P2l = P2h + (size_t)NNODES * 256;
    short* GPh = (short*)g;  // pool out planes, stride 128
    short* GPl = GPh + (size_t)NGRAPHS * 128;
    short* GHh = (short*)gh;  // fc0 out planes, stride 1024
    short* GHl = GHh + (size_t)NGRAPHS * 1024;

    const int GB2 = (NNODES + 127) / 128;  // 782 row-blocks (MROWS=2)
    const int NB = (NNODES + 255) / 256;   // 391 scan blocks
    const int EB = (NEDGES + 255) / 256;   // edge blocks

    // --- build CSR + graph bounds (single atomic pass, line-padded counters) ---
    hipMemsetAsync(degp, 0, (size_t)NNODES * 16 * sizeof(int), stream);
    hipMemsetAsync(stats0, 0, 1536 * sizeof(float), stream);  // all 3 stats buffers
    pad66_kernel<<<(NNODES * 17 + 255) / 256, 256, 0, stream>>>(x, xpad);
    degoff_kernel<<<EB, 256, 0, stream>>>(dstA, degp, off);
    scan1_kernel<<<NB, 256, 0, stream>>>(degp, partials);
    scan2_kernel<<<1, 512, 0, stream>>>(partials, NB);
    scan3_kernel<<<NB, 256, 0, stream>>>(degp, partials, rowptr, batch, gstart);
    fill2_kernel<<<EB, 256, 0, stream>>>(srcA, rowptr, off, adj);

    // --- W-fragment pre-pass: one dispatch for all 8 weights ---
    {
        WDescs wd;
        const float* Wp[8] = {g0_w1, g0_w2, g1_w1, g1_w2, g2_w1, g2_w2, fc0_w, fc1_w};
        const int Kw[8] = {66, 128, 128, 256, 256, 128, 128, 1024};
        const int Nn[8] = {128, 128, 256, 256, 128, 128, 1024, 128};
        const int KT[8] = {3, 4, 4, 8, 8, 4, 4, 32};
        int cum = 0;
        wd.cum[0] = 0;
        for (int i = 0; i < 8; ++i) {
            wd.d[i].W = Wp[i];
            wd.d[i].Kw = Kw[i];
            wd.d[i].N = Nn[i];
            wd.d[i].KT = KT[i];
            wd.d[i].hioff = (int)(whi[i] - wf);
            wd.d[i].looff = (int)(wlo[i] - wf);
            cum += (Nn[i] >> 4) * KT[i] * 512;
            wd.cum[i + 1] = cum;
        }
        wprep_all_kernel<<<(wd.cum[8] + 255) / 256, 256, 0, stream>>>(wd, wf);
    }

    // ================= Layer 0 (66 -> 128 -> 128) =================
    // gather xpad (stride 68, 16B requests) -> P0 planes in R0; xpad (R1) dies when
    // L0a writes R1.
    gather_kernel<68, 4, 96, true><<<(NNODES * 24 + 255) / 256, 256, 0, stream>>>(
        xpad, rowptr, adj, nullptr, P0h, P0l, nullptr);
    gemm_mfma_kernel<8, 3, 3, 2, false, false, true, false, true, false, 3>
        <<<GB2, 256, 0, stream>>>(nullptr, P0h, P0l, whi[0], wlo[0], g0_b1, nullptr, nullptr, R1,
                                  nullptr, nullptr, stats0, NNODES, 96, 128);
    gemm_mfma_kernel<8, 4, 4, 2, true, true, false, false, false, false, 3>
        <<<GB2, 256, 0, stream>>>(R1, nullptr, nullptr, whi[1], wlo[1], g0_b2, g0_ga, g0_be, R0,
                                  nullptr, nullptr, stats0, NNODES, 128, 128);

    // ================= Layer 1 (128 -> 256 -> 256) =================
    gather_kernel<128, 4, 128, true><<<(NNODES * 32 + 255) / 256, 256, 0, stream>>>(
        R0, rowptr, adj, nullptr, P1h, P1l, nullptr);
    gemm_mfma_kernel<8, 4, 4, 2, false, false, true, false, true, false, 3>
        <<<dim3(GB2, 2), 256, 0, stream>>>(nullptr, P1h, P1l, whi[2], wlo[2], g1_b1, nullptr,
                                           nullptr, R0, nullptr, nullptr, stats1, NNODES, 128,
                                           256);
    gemm_mfma_kernel<8, 8, 8, 2, true, true, false, false, false, true, 3>
        <<<dim3(GB2, 2), 256, 0, stream>>>(R0, nullptr, nullptr, whi[3], wlo[3], g1_b2, g1_ga,
                                           g1_be, nullptr, P2h, P2l, stats1, NNODES, 256, 256);

    // ================= Layer 2 (256 -> 128 -> 128), REORDERED =================
    gemm_mfma_kernel<8, 8, 8, 2, false, false, false, false, true, false, 3>
        <<<GB2, 256, 0, stream>>>(nullptr, P2h, P2l, whi[4], wlo[4], nullptr, nullptr, nullptr,
                                  R0, nullptr, nullptr, nullptr, NNODES, 256, 128);
    gather_kernel<128, 4, 128, false><<<(NNODES * 32 + 255) / 256, 256, 0, stream>>>(
        R0, rowptr, adj, R1, nullptr, nullptr, g2_b1);
    bnstats_kernel<128><<<256, 256, 0, stream>>>(R1, stats2);
    gemm_mfma_kernel<8, 4, 4, 2, true, true, false, false, false, false, 3>
        <<<GB2, 256, 0, stream>>>(R1, nullptr, nullptr, whi[5], wlo[5], g2_b2, g2_ga, g2_be, R0,
                                  nullptr, nullptr, stats2, NNODES, 128, 128);

    // ================= pool + FC head (all MFMA, all ASPLIT) =================
    pool_seg_kernel<true><<<NGRAPHS, 128, 0, stream>>>(R0, gstart, nullptr, GPh, GPl);

    // fc0: relu(g @ fc0_w + fc0_b) -> gh planes. grid (2048/128, 1024/(8*16)) = (16, 8).
    gemm_mfma_kernel<8, 4, 4, 2, false, true, false, false, true, true, 3>
        <<<dim3(NGRAPHS / 128, 8), 256, 0, stream>>>(nullptr, GPh, GPl, whi[6], wlo[6], fc0_b,
                                                     nullptr, nullptr, nullptr, GHh, GHl, nullptr,
                                                     NGRAPHS, 128, 1024);
    // fc1 split-K: 8 chunks of KTLOOP=4 over KTT=32 -> partials in R1, then reduce+bias.
    gemm_mfma_kernel<8, 4, 32, 2, false, false, false, true, true, false, 3>
        <<<dim3(NGRAPHS / 128, 1, 8), 256, 0, stream>>>(nullptr, GHh, GHl, whi[7], wlo[7], nullptr,
                                                        nullptr, nullptr, R1, nullptr, nullptr,
                                                        nullptr, NGRAPHS, 1024, 128);
    splitk_reduce_kernel<<<(NGRAPHS * 128 / 4 + 255) / 256, 256, 0, stream>>>(R1, fc1_b,
                                                                              (float*)d_out);
}

// Round 10
// 1127.943 us; speedup vs baseline: 1.0298x; 1.0298x over previous
//
#include <hip/hip_runtime.h>

#define NNODES 100000
#define NEDGES 1600000
#define NGRAPHS 2048
#define BN_EPS 1e-5f

typedef __attribute__((ext_vector_type(8))) short bf16x8;
typedef __attribute__((ext_vector_type(4))) float f32x4;

// RNE float -> bf16 (as short bits)
__device__ __forceinline__ short f2bf(float x) {
    unsigned u = __float_as_uint(x);
    unsigned r = u + 0x7FFF + ((u >> 16) & 1);
    return (short)(r >> 16);
}
__device__ __forceinline__ float bf2f(short h) {
    return __uint_as_float(((unsigned)(unsigned short)h) << 16);
}

// ---------------- CSR build ----------------
// Single atomic pass with line-padded counters; fill pass atomic-free.
__global__ __launch_bounds__(256) void degoff_kernel(const int* __restrict__ dstA,
                                                     int* __restrict__ degp,
                                                     int* __restrict__ off) {
    int e = blockIdx.x * 256 + threadIdx.x;
    if (e < NEDGES) {
        int d = dstA[e];
        int c = atomicAdd(&degp[d << 4], 1);  // padded: 1 counter per 64B line
        off[e] = (d << 8) | c;                // max deg ~35 << 256 for uniform-random edges
    }
}

__global__ __launch_bounds__(256) void scan1_kernel(const int* __restrict__ degp,
                                                    int* __restrict__ partials) {
    int b = blockIdx.x;
    int i = b * 256 + threadIdx.x;
    int v = (i < NNODES) ? degp[i << 4] : 0;
    __shared__ int wsum[4];
#pragma unroll
    for (int off = 32; off; off >>= 1) v += __shfl_down(v, off);
    if ((threadIdx.x & 63) == 0) wsum[threadIdx.x >> 6] = v;
    __syncthreads();
    if (threadIdx.x == 0) partials[b] = wsum[0] + wsum[1] + wsum[2] + wsum[3];
}

__global__ __launch_bounds__(512) void scan2_kernel(int* __restrict__ partials, int nb) {
    __shared__ int s[512];
    int t = threadIdx.x;
    int v = (t < nb) ? partials[t] : 0;
    s[t] = v;
    __syncthreads();
    for (int off = 1; off < 512; off <<= 1) {
        int u = (t >= off) ? s[t - off] : 0;
        __syncthreads();
        s[t] += u;
        __syncthreads();
    }
    if (t < nb) partials[t] = s[t] - v;  // exclusive
}

__global__ __launch_bounds__(256) void scan3_kernel(const int* __restrict__ degp,
                                                    const int* __restrict__ partials,
                                                    int* __restrict__ rowptr,
                                                    const int* __restrict__ batch,
                                                    int* __restrict__ gstart) {
    int b = blockIdx.x;
    int t = threadIdx.x;
    int i = b * 256 + t;
    __shared__ int s[256];
    int v = (i < NNODES) ? degp[i << 4] : 0;
    s[t] = v;
    __syncthreads();
    for (int off = 1; off < 256; off <<= 1) {
        int u = (t >= off) ? s[t - off] : 0;
        __syncthreads();
        s[t] += u;
        __syncthreads();
    }
    if (i < NNODES) {
        int ex = partials[b] + s[t] - v;
        rowptr[i] = ex;
        int bb = batch[i];
        int bp = (i == 0) ? -1 : batch[i - 1];
        for (int g = bp + 1; g <= bb; ++g) gstart[g] = i;
        if (i == NNODES - 1)
            for (int g = bb + 1; g <= NGRAPHS; ++g) gstart[g] = NNODES;
    }
    if (b == 0 && t == 0) rowptr[NNODES] = NEDGES;
}

__global__ __launch_bounds__(256) void fill2_kernel(const int* __restrict__ srcA,
                                                    const int* __restrict__ rowptr,
                                                    const int* __restrict__ off,
                                                    int* __restrict__ adj) {
    int e = blockIdx.x * 256 + threadIdx.x;
    if (e < NEDGES) {
        int v = off[e];
        adj[rowptr[v >> 8] + (v & 255)] = srcA[e];  // no atomic; rowptr is L2-resident
    }
}

// ---- pad x (NNODES x 66 fp32) into stride-68 rows so the L0 gather can use 16B
// requests (R7 evidence: gathers are request-rate bound). Exact copy + zeros.
__global__ __launch_bounds__(256) void pad66_kernel(const float* __restrict__ x,
                                                    float* __restrict__ xpad) {
    int idx = blockIdx.x * 256 + threadIdx.x;
    if (idx >= NNODES * 17) return;
    int node = idx / 17;
    int c = idx - node * 17;
    float4 v;
    if (c < 16) {
        float2 a = *(const float2*)&x[(size_t)node * 66 + c * 4];
        float2 b = *(const float2*)&x[(size_t)node * 66 + c * 4 + 2];
        v = make_float4(a.x, a.y, b.x, b.y);
    } else {
        float2 a = *(const float2*)&x[(size_t)node * 66 + 64];
        v = make_float4(a.x, a.y, 0.f, 0.f);
    }
    *(float4*)&xpad[(size_t)node * 68 + c * 4] = v;
}

// ------- gather aggregation: agg[n] = x[n] + sum_{s in adj[n]} x[s] (+bias) -------
// Fabric/request ceiling bound. Unroll 8 => 8 outstanding row loads/thread.
// SPLIT epilogue emits hi/lo bf16 planes for the ASPLIT GEMM consumer.
template <int DIM, int CHUNK, int OSTRIDE, bool SPLIT>
__global__ __launch_bounds__(256) void gather_kernel(const float* __restrict__ x,
                                                     const int* __restrict__ rowptr,
                                                     const int* __restrict__ adj,
                                                     float* __restrict__ agg,
                                                     short* __restrict__ oh,
                                                     short* __restrict__ ol,
                                                     const float* __restrict__ bias) {
    constexpr int PE = DIM / CHUNK;
    constexpr int PEL = SPLIT ? (OSTRIDE / CHUNK) : PE;
    int gid = blockIdx.x * 256 + threadIdx.x;
    if (gid >= NNODES * PEL) return;
    int node = gid / PEL;
    int c = gid - node * PEL;
    if constexpr (SPLIT) {
        if (c >= PE) {  // zero-pad columns [DIM, OSTRIDE)
            size_t o = (size_t)node * OSTRIDE + c * CHUNK;
            if constexpr (CHUNK == 4) {
                short4 z;
                z.x = z.y = z.z = z.w = 0;
                *(short4*)&oh[o] = z;
                *(short4*)&ol[o] = z;
            } else {
                short2 z;
                z.x = z.y = 0;
                *(short2*)&oh[o] = z;
                *(short2*)&ol[o] = z;
            }
            return;
        }
    }
    const int beg = rowptr[node];
    const int end = rowptr[node + 1];
    if constexpr (CHUNK == 4) {
        const float4* xp = (const float4*)x;
        float4 acc = xp[(size_t)node * PE + c];
        float4 acc1 = make_float4(0.f, 0.f, 0.f, 0.f);
        int i = beg;
        for (; i + 8 <= end; i += 8) {
            int s0 = adj[i + 0], s1 = adj[i + 1], s2 = adj[i + 2], s3 = adj[i + 3];
            int s4 = adj[i + 4], s5 = adj[i + 5], s6 = adj[i + 6], s7 = adj[i + 7];
            float4 v0 = xp[(size_t)s0 * PE + c];
            float4 v1 = xp[(size_t)s1 * PE + c];
            float4 v2 = xp[(size_t)s2 * PE + c];
            float4 v3 = xp[(size_t)s3 * PE + c];
            float4 v4 = xp[(size_t)s4 * PE + c];
            float4 v5 = xp[(size_t)s5 * PE + c];
            float4 v6 = xp[(size_t)s6 * PE + c];
            float4 v7 = xp[(size_t)s7 * PE + c];
            acc.x += v0.x + v1.x; acc.y += v0.y + v1.y; acc.z += v0.z + v1.z; acc.w += v0.w + v1.w;
            acc1.x += v2.x + v3.x; acc1.y += v2.y + v3.y; acc1.z += v2.z + v3.z; acc1.w += v2.w + v3.w;
            acc.x += v4.x + v5.x; acc.y += v4.y + v5.y; acc.z += v4.z + v5.z; acc.w += v4.w + v5.w;
            acc1.x += v6.x + v7.x; acc1.y += v6.y + v7.y; acc1.z += v6.z + v7.z; acc1.w += v6.w + v7.w;
        }
        for (; i + 4 <= end; i += 4) {
            int s0 = adj[i + 0], s1 = adj[i + 1], s2 = adj[i + 2], s3 = adj[i + 3];
            float4 v0 = xp[(size_t)s0 * PE + c];
            float4 v1 = xp[(size_t)s1 * PE + c];
            float4 v2 = xp[(size_t)s2 * PE + c];
            float4 v3 = xp[(size_t)s3 * PE + c];
            acc.x += v0.x + v1.x; acc.y += v0.y + v1.y; acc.z += v0.z + v1.z; acc.w += v0.w + v1.w;
            acc1.x += v2.x + v3.x; acc1.y += v2.y + v3.y; acc1.z += v2.z + v3.z; acc1.w += v2.w + v3.w;
        }
        for (; i < end; ++i) {
            int s = adj[i];
            float4 v = xp[(size_t)s * PE + c];
            acc.x += v.x; acc.y += v.y; acc.z += v.z; acc.w += v.w;
        }
        acc.x += acc1.x; acc.y += acc1.y; acc.z += acc1.z; acc.w += acc1.w;
        if (bias) {
            float4 b = *(const float4*)&bias[c * 4];
            acc.x += b.x; acc.y += b.y; acc.z += b.z; acc.w += b.w;
        }
        if constexpr (SPLIT) {
            size_t o = (size_t)node * OSTRIDE + c * 4;
            short4 h4, l4;
            h4.x = f2bf(acc.x); l4.x = f2bf(acc.x - bf2f(h4.x));
            h4.y = f2bf(acc.y); l4.y = f2bf(acc.y - bf2f(h4.y));
            h4.z = f2bf(acc.z); l4.z = f2bf(acc.z - bf2f(h4.z));
            h4.w = f2bf(acc.w); l4.w = f2bf(acc.w - bf2f(h4.w));
            *(short4*)&oh[o] = h4;
            *(short4*)&ol[o] = l4;
        } else {
            *(float4*)&agg[(size_t)node * OSTRIDE + c * 4] = acc;
        }
    } else {
        const float2* xp = (const float2*)x;
        float2 acc = xp[(size_t)node * PE + c];
        float2 acc1 = make_float2(0.f, 0.f);
        int i = beg;
        for (; i + 8 <= end; i += 8) {
            int s0 = adj[i + 0], s1 = adj[i + 1], s2 = adj[i + 2], s3 = adj[i + 3];
            int s4 = adj[i + 4], s5 = adj[i + 5], s6 = adj[i + 6], s7 = adj[i + 7];
            float2 v0 = xp[(size_t)s0 * PE + c];
            float2 v1 = xp[(size_t)s1 * PE + c];
            float2 v2 = xp[(size_t)s2 * PE + c];
            float2 v3 = xp[(size_t)s3 * PE + c];
            float2 v4 = xp[(size_t)s4 * PE + c];
            float2 v5 = xp[(size_t)s5 * PE + c];
            float2 v6 = xp[(size_t)s6 * PE + c];
            float2 v7 = xp[(size_t)s7 * PE + c];
            acc.x += v0.x + v1.x; acc.y += v0.y + v1.y;
            acc1.x += v2.x + v3.x; acc1.y += v2.y + v3.y;
            acc.x += v4.x + v5.x; acc.y += v4.y + v5.y;
            acc1.x += v6.x + v7.x; acc1.y += v6.y + v7.y;
        }
        for (; i + 4 <= end; i += 4) {
            int s0 = adj[i + 0], s1 = adj[i + 1], s2 = adj[i + 2], s3 = adj[i + 3];
            float2 v0 = xp[(size_t)s0 * PE + c];
            float2 v1 = xp[(size_t)s1 * PE + c];
            float2 v2 = xp[(size_t)s2 * PE + c];
            float2 v3 = xp[(size_t)s3 * PE + c];
            acc.x += v0.x + v1.x; acc.y += v0.y + v1.y;
            acc1.x += v2.x + v3.x; acc1.y += v2.y + v3.y;
        }
        for (; i < end; ++i) {
            int s = adj[i];
            float2 v = xp[(size_t)s * PE + c];
            acc.x += v.x; acc.y += v.y;
        }
        acc.x += acc1.x; acc.y += acc1.y;
        if constexpr (SPLIT) {
            size_t o = (size_t)node * OSTRIDE + c * 2;
            short2 h2, l2;
            h2.x = f2bf(acc.x); l2.x = f2bf(acc.x - bf2f(h2.x));
            h2.y = f2bf(acc.y); l2.y = f2bf(acc.y - bf2f(h2.y));
            *(short2*)&oh[o] = h2;
            *(short2*)&ol[o] = l2;
        } else {
            *(float2*)&agg[(size_t)node * OSTRIDE + c * 2] = acc;
        }
    }
}

// ---------------- BN stats (standalone, used once for L2) ----------------
template <int N>
__global__ __launch_bounds__(256) void bnstats_kernel(const float* __restrict__ h,
                                                      float* __restrict__ sums) {
    constexpr int SHIFT = (N == 128) ? 7 : 8;
    int t = blockIdx.x * 256 + threadIdx.x;
    int col = t & (N - 1);
    int slice = t >> SHIFT;
    int stride = (gridDim.x * 256) >> SHIFT;
    float s = 0.f, s2 = 0.f;
    for (int r = slice; r < NNODES; r += stride) {
        float v = h[(size_t)r * N + col];
        s += v;
        s2 += v * v;
    }
    atomicAdd(&sums[col], s);
    atomicAdd(&sums[256 + col], s2);
}

// reads sums (sum@c, sumsq@256+c), writes scale@c / shift@256+c, then re-zeroes sums.
__global__ void bnfinal_kernel(float* __restrict__ sums, const float* __restrict__ gamma,
                               const float* __restrict__ beta, float* __restrict__ scsh, int N,
                               float invM) {
    int c = threadIdx.x;  // 256 threads always
    if (c < N) {
        float mean = sums[c] * invM;
        float var = sums[256 + c] * invM - mean * mean;
        float sc = gamma[c] * rsqrtf(var + BN_EPS);
        scsh[c] = sc;
        scsh[256 + c] = beta[c] - mean * sc;
    }
    sums[c] = 0.f;
    sums[256 + c] = 0.f;
}

// ---- W pre-pass (ALL weights in ONE dispatch): decompose W into hi/lo bf16 B-frags ----
// B-frag layout (mfma_f32_16x16x32_bf16): lane holds n=lane&15, k=(lane>>4)*8+j.
// Buffer index: ((nt*KT + kt)*64 + lane)*8 + j.
struct WDesc {
    const float* W;
    int Kw, N, KT, hioff, looff;
};
struct WDescs {
    WDesc d[8];
    int cum[9];
};
__global__ __launch_bounds__(256) void wprep_all_kernel(WDescs wd, short* __restrict__ wf) {
    int idx = blockIdx.x * 256 + threadIdx.x;
    if (idx >= wd.cum[8]) return;
    int s = 0;
#pragma unroll
    for (int i = 1; i < 8; ++i) s += (idx >= wd.cum[i]);
    int r = idx - wd.cum[s];
    const WDesc D = wd.d[s];
    int j = r & 7;
    int lane = (r >> 3) & 63;
    int t = r >> 9;  // nt*KT + kt
    int kt = t % D.KT;
    int nt = t / D.KT;
    int k = kt * 32 + ((lane >> 4) << 3) + j;
    int n = (nt << 4) + (lane & 15);
    float w = (k < D.Kw) ? D.W[(size_t)k * D.N + n] : 0.f;
    short hi = f2bf(w);
    wf[D.hioff + r] = hi;
    wf[D.looff + r] = f2bf(w - bf2f(hi));
}

// ---------------- split-bf16 MFMA GEMM: C = op(A) @ W + bias ----------------
// LDS-free. Block = 4 waves; BM = 64*MROWS (each wave computes MROWS 16-row tiles);
// NT N-tiles per block (grid.y splits N). MROWS=2 everywhere (R6/R7 verified; R8's
// MROWS=3/MINW=2 regressed occupancy; R9's inline-bnfinal perturbed codegen VGPR
// 52->68 and regressed — reverted to the exact R7-measured configuration). Simple
// codegen retained (R5 spill lesson: no register queues). MFMA order per output row
// unchanged => bit-identical results.
template <int NT, int KTLOOP, int KTT, int MROWS, bool BNRELU_A, bool RELU_OUT, bool FUSE_STATS,
          bool SPLITK, bool ASPLIT, bool SPLIT_OUT, int MINW>
__global__ __launch_bounds__(256, MINW) void gemm_mfma_kernel(
    const float* __restrict__ A, const short* __restrict__ Ah, const short* __restrict__ Al,
    const short* __restrict__ whi, const short* __restrict__ wlo, const float* __restrict__ bias,
    const float* __restrict__ scsh, float* __restrict__ C, short* __restrict__ Ch,
    short* __restrict__ Cl, float* __restrict__ stats, int M, int Kst, int N) {
    __shared__ float sstat[512];
    const int tid = threadIdx.x;
    const int wave = tid >> 6;
    const int lane = tid & 63;
    const int quad = lane >> 4;
    const int l16 = lane & 15;
    const int mrow = blockIdx.x * (64 * MROWS) + wave * 16 + l16;
    const int ngrp = blockIdx.y * NT * 16;
    const size_t wgrp = (size_t)blockIdx.y * NT * KTT * 512;
    const int ktbeg = SPLITK ? blockIdx.z * KTLOOP : 0;
    float* Cb = SPLITK ? C + (size_t)blockIdx.z * M * N : C;

    if (FUSE_STATS) {
        sstat[tid] = 0.f;
        sstat[tid + 256] = 0.f;
        __syncthreads();
    }

    f32x4 acc[MROWS][NT] = {};

    auto kstep = [&](int kt) {
        const int kq = kt * 32 + quad * 8;
        bf16x8 ahi[MROWS], alo[MROWS];
        if constexpr (ASPLIT) {
#pragma unroll
            for (int m = 0; m < MROWS; ++m) {
                const size_t ro = (size_t)(mrow + m * 64) * Kst + kq;
                ahi[m] = *(const bf16x8*)(Ah + ro);
                alo[m] = *(const bf16x8*)(Al + ro);
            }
        } else {
            float sc[8], sh[8];
            if constexpr (BNRELU_A) {
                float4 sc0 = *(const float4*)&scsh[kq];
                float4 sc1 = *(const float4*)&scsh[kq + 4];
                float4 sh0 = *(const float4*)&scsh[256 + kq];
                float4 sh1 = *(const float4*)&scsh[256 + kq + 4];
                sc[0] = sc0.x; sc[1] = sc0.y; sc[2] = sc0.z; sc[3] = sc0.w;
                sc[4] = sc1.x; sc[5] = sc1.y; sc[6] = sc1.z; sc[7] = sc1.w;
                sh[0] = sh0.x; sh[1] = sh0.y; sh[2] = sh0.z; sh[3] = sh0.w;
                sh[4] = sh1.x; sh[5] = sh1.y; sh[6] = sh1.z; sh[7] = sh1.w;
            }
#pragma unroll
            for (int m = 0; m < MROWS; ++m) {
                const float* ap = A + (size_t)(mrow + m * 64) * Kst + kq;
                float4 x0 = *(const float4*)ap;
                float4 x1 = *(const float4*)(ap + 4);
                float a8[8] = {x0.x, x0.y, x0.z, x0.w, x1.x, x1.y, x1.z, x1.w};
                if constexpr (BNRELU_A) {
#pragma unroll
                    for (int i = 0; i < 8; ++i) a8[i] = fmaxf(a8[i] * sc[i] + sh[i], 0.f);
                }
#pragma unroll
                for (int i = 0; i < 8; ++i) {
                    short h = f2bf(a8[i]);
                    ahi[m][i] = h;
                    alo[m][i] = f2bf(a8[i] - bf2f(h));
                }
            }
        }
#pragma unroll
        for (int nt = 0; nt < NT; ++nt) {
            const size_t boff = wgrp + (((size_t)nt * KTT + kt) << 9) + ((size_t)lane << 3);
            bf16x8 bh = *(const bf16x8*)(whi + boff);
            bf16x8 bl = *(const bf16x8*)(wlo + boff);
#pragma unroll
            for (int m = 0; m < MROWS; ++m) {
                acc[m][nt] = __builtin_amdgcn_mfma_f32_16x16x32_bf16(ahi[m], bh, acc[m][nt], 0, 0, 0);
                acc[m][nt] = __builtin_amdgcn_mfma_f32_16x16x32_bf16(alo[m], bh, acc[m][nt], 0, 0, 0);
                acc[m][nt] = __builtin_amdgcn_mfma_f32_16x16x32_bf16(ahi[m], bl, acc[m][nt], 0, 0, 0);
                acc[m][nt] = __builtin_amdgcn_mfma_f32_16x16x32_bf16(alo[m], bl, acc[m][nt], 0, 0, 0);
            }
        }
    };

    if constexpr (ASPLIT) {
#pragma unroll 2
        for (int k = 0; k < KTLOOP; ++k) kstep(ktbeg + k);
    } else {
#pragma unroll 1
        for (int k = 0; k < KTLOOP; ++k) kstep(ktbeg + k);
    }

    // Epilogue. C/D frag: col = l16 (+16*nt), row = quad*4 + reg (m89-verified).
#pragma unroll
    for (int m = 0; m < MROWS; ++m) {
        const int mbase = blockIdx.x * (64 * MROWS) + m * 64 + wave * 16 + quad * 4;
#pragma unroll
        for (int nt = 0; nt < NT; ++nt) {
            int gn = ngrp + nt * 16 + l16;
            float bv = bias ? bias[gn] : 0.f;
            float s = 0.f, s2 = 0.f;
#pragma unroll
            for (int r = 0; r < 4; ++r) {
                int gm = mbase + r;
                float v = acc[m][nt][r] + bv;
                if (RELU_OUT) v = fmaxf(v, 0.f);
                if (gm < M) {
                    if constexpr (SPLIT_OUT) {
                        short h = f2bf(v);
                        Ch[(size_t)gm * N + gn] = h;
                        Cl[(size_t)gm * N + gn] = f2bf(v - bf2f(h));
                    } else {
                        Cb[(size_t)gm * N + gn] = v;
                    }
                    if (FUSE_STATS) {
                        s += v;
                        s2 += v * v;
                    }
                }
            }
            if (FUSE_STATS) {
                s += __shfl_xor(s, 16);
                s += __shfl_xor(s, 32);
                s2 += __shfl_xor(s2, 16);
                s2 += __shfl_xor(s2, 32);
                if (quad == 0) {
                    atomicAdd(&sstat[gn], s);
                    atomicAdd(&sstat[256 + gn], s2);
                }
            }
        }
    }
    if (FUSE_STATS) {
        __syncthreads();
        if (tid < N) {
            atomicAdd(&stats[tid], sstat[tid]);
            atomicAdd(&stats[256 + tid], sstat[256 + tid]);
        }
    }
}

// ---- reduce 8 split-K partials + bias -> out (fc1: M=2048,N=128) ----
__global__ __launch_bounds__(256) void splitk_reduce_kernel(const float* __restrict__ part,
                                                            const float* __restrict__ bias,
                                                            float* __restrict__ out) {
    const int i4 = blockIdx.x * 256 + threadIdx.x;
    const int TOT4 = NGRAPHS * 128 / 4;  // 65536
    if (i4 >= TOT4) return;
    const float4* p = (const float4*)part;
    float4 acc = make_float4(0.f, 0.f, 0.f, 0.f);
#pragma unroll
    for (int c = 0; c < 8; ++c) {
        float4 v = p[(size_t)c * TOT4 + i4];
        acc.x += v.x;
        acc.y += v.y;
        acc.z += v.z;
        acc.w += v.w;
    }
    float4 b = ((const float4*)bias)[i4 & 31];
    acc.x += b.x;
    acc.y += b.y;
    acc.z += b.z;
    acc.w += b.w;
    ((float4*)out)[i4] = acc;
}

// ---- segmented pool over sorted batch; SPLIT emits hi/lo planes for fc0 ----
template <bool SPLIT>
__global__ __launch_bounds__(128) void pool_seg_kernel(const float* __restrict__ h,
                                                       const int* __restrict__ gstart,
                                                       float* __restrict__ g,
                                                       short* __restrict__ oh,
                                                       short* __restrict__ ol) {
    int gr = blockIdx.x;
    int t = threadIdx.x;
    int beg = gstart[gr];
    int end = gstart[gr + 1];
    float acc = 0.f;
    for (int r = beg; r < end; ++r) acc += h[(size_t)r * 128 + t];
    if constexpr (SPLIT) {
        short hh = f2bf(acc);
        oh[(size_t)gr * 128 + t] = hh;
        ol[(size_t)gr * 128 + t] = f2bf(acc - bf2f(hh));
    } else {
        g[(size_t)gr * 128 + t] = acc;
    }
}

extern "C" void kernel_launch(void* const* d_in, const int* in_sizes, int n_in, void* d_out,
                              int out_size, void* d_ws, size_t ws_size, hipStream_t stream) {
    const float* x = (const float*)d_in[0];
    const int* ei = (const int*)d_in[1];
    const int* batch = (const int*)d_in[2];
    const int* srcA = ei;
    const int* dstA = ei + NEDGES;

    const float* g0_w1 = (const float*)d_in[3];
    const float* g0_b1 = (const float*)d_in[4];
    const float* g0_ga = (const float*)d_in[5];
    const float* g0_be = (const float*)d_in[6];
    const float* g0_w2 = (const float*)d_in[7];
    const float* g0_b2 = (const float*)d_in[8];
    const float* g1_w1 = (const float*)d_in[9];
    const float* g1_b1 = (const float*)d_in[10];
    const float* g1_ga = (const float*)d_in[11];
    const float* g1_be = (const float*)d_in[12];
    const float* g1_w2 = (const float*)d_in[13];
    const float* g1_b2 = (const float*)d_in[14];
    const float* g2_w1 = (const float*)d_in[15];
    const float* g2_b1 = (const float*)d_in[16];
    const float* g2_ga = (const float*)d_in[17];
    const float* g2_be = (const float*)d_in[18];
    const float* g2_w2 = (const float*)d_in[19];
    const float* g2_b2 = (const float*)d_in[20];
    const float* fc0_w = (const float*)d_in[21];
    const float* fc0_b = (const float*)d_in[22];
    const float* fc1_w = (const float*)d_in[23];
    const float* fc1_b = (const float*)d_in[24];

    // --- workspace layout ---
    float* ws = (float*)d_ws;
    const size_t BUF = (size_t)NNODES * 256;
    float* R0 = ws;
    float* R1 = R0 + BUF;  // also fc1 split-K partial buffer (8*2048*128 floats)
    float* stats = R1 + BUF;                            // 512
    float* scsh = stats + 512;                          // 512
    float* g = scsh + 512;                              // 2048*128 pooled
    float* gh = g + (size_t)NGRAPHS * 128;              // 2048*1024 fc hidden
    int* rowptr = (int*)(gh + (size_t)NGRAPHS * 1024);  // NNODES+1
    int* adj = rowptr + NNODES + 4;                     // NEDGES
    int* partials = adj + NEDGES;                       // 391
    int* gstart = partials + 512;                       // NGRAPHS+1
    short* wf = (short*)(gstart + 2052);                // W-fragment arena

    // CSR scratch overlays dead R0 (R0 first written by L0 gather, after fill2):
    int* degp = (int*)R0;           // NNODES*16 ints (padded counters, 1/line)
    int* off = degp + NNODES * 16;  // NEDGES packed (dst<<8)|slot
    // Padded-x overlay in R1 (dead until L0a writes R1; gather reads it before that):
    float* xpad = R1;  // NNODES*68 floats (~27 MB)

    short* whi[8];
    short* wlo[8];
    for (int i = 0; i < 6; ++i) {
        whi[i] = wf + (size_t)i * 131072;
        wlo[i] = whi[i] + 65536;
    }
    whi[6] = wf + 6 * 131072;
    wlo[6] = whi[6] + 131072;
    whi[7] = whi[6] + 262144;
    wlo[7] = whi[7] + 131072;

    // bf16 A-plane overlays (hi plane then lo plane, both stride = padded K):
    short* P0h = (short*)R0;  // L0 gather out, stride 96 (cols 66..95 zeroed)
    short* P0l = P0h + (size_t)NNODES * 96;
    short* P1h = (short*)R1;  // L1 gather out, stride 128
    short* P1l = P1h + (size_t)NNODES * 128;
    short* P2h = (short*)R1;  // L1b out, stride 256 (fills R1 exactly)
    short* P2l = P2h + (size_t)NNODES * 256;
    short* GPh = (short*)g;  // pool out planes, stride 128
    short* GPl = GPh + (size_t)NGRAPHS * 128;
    short* GHh = (short*)gh;  // fc0 out planes, stride 1024
    short* GHl = GHh + (size_t)NGRAPHS * 1024;

    const int GB2 = (NNODES + 127) / 128;  // 782 row-blocks (MROWS=2)
    const int NB = (NNODES + 255) / 256;   // 391 scan blocks
    const int EB = (NEDGES + 255) / 256;   // edge blocks

    // --- build CSR + graph bounds (single atomic pass, line-padded counters) ---
    hipMemsetAsync(degp, 0, (size_t)NNODES * 16 * sizeof(int), stream);
    hipMemsetAsync(stats, 0, 512 * sizeof(float), stream);  // bnfinal re-zeroes thereafter
    pad66_kernel<<<(NNODES * 17 + 255) / 256, 256, 0, stream>>>(x, xpad);
    degoff_kernel<<<EB, 256, 0, stream>>>(dstA, degp, off);
    scan1_kernel<<<NB, 256, 0, stream>>>(degp, partials);
    scan2_kernel<<<1, 512, 0, stream>>>(partials, NB);
    scan3_kernel<<<NB, 256, 0, stream>>>(degp, partials, rowptr, batch, gstart);
    fill2_kernel<<<EB, 256, 0, stream>>>(srcA, rowptr, off, adj);

    // --- W-fragment pre-pass: one dispatch for all 8 weights ---
    {
        WDescs wd;
        const float* Wp[8] = {g0_w1, g0_w2, g1_w1, g1_w2, g2_w1, g2_w2, fc0_w, fc1_w};
        const int Kw[8] = {66, 128, 128, 256, 256, 128, 128, 1024};
        const int Nn[8] = {128, 128, 256, 256, 128, 128, 1024, 128};
        const int KT[8] = {3, 4, 4, 8, 8, 4, 4, 32};
        int cum = 0;
        wd.cum[0] = 0;
        for (int i = 0; i < 8; ++i) {
            wd.d[i].W = Wp[i];
            wd.d[i].Kw = Kw[i];
            wd.d[i].N = Nn[i];
            wd.d[i].KT = KT[i];
            wd.d[i].hioff = (int)(whi[i] - wf);
            wd.d[i].looff = (int)(wlo[i] - wf);
            cum += (Nn[i] >> 4) * KT[i] * 512;
            wd.cum[i + 1] = cum;
        }
        wprep_all_kernel<<<(wd.cum[8] + 255) / 256, 256, 0, stream>>>(wd, wf);
    }

    // ================= Layer 0 (66 -> 128 -> 128) =================
    // gather xpad (stride 68, 16B requests) -> P0 planes in R0; xpad (R1) dies when
    // L0a writes R1.
    gather_kernel<68, 4, 96, true><<<(NNODES * 24 + 255) / 256, 256, 0, stream>>>(
        xpad, rowptr, adj, nullptr, P0h, P0l, nullptr);
    gemm_mfma_kernel<8, 3, 3, 2, false, false, true, false, true, false, 3>
        <<<GB2, 256, 0, stream>>>(nullptr, P0h, P0l, whi[0], wlo[0], g0_b1, nullptr, R1, nullptr,
                                  nullptr, stats, NNODES, 96, 128);
    bnfinal_kernel<<<1, 256, 0, stream>>>(stats, g0_ga, g0_be, scsh, 128, 1.0f / NNODES);
    gemm_mfma_kernel<8, 4, 4, 2, true, true, false, false, false, false, 3>
        <<<GB2, 256, 0, stream>>>(R1, nullptr, nullptr, whi[1], wlo[1], g0_b2, scsh, R0, nullptr,
                                  nullptr, nullptr, NNODES, 128, 128);

    // ================= Layer 1 (128 -> 256 -> 256) =================
    gather_kernel<128, 4, 128, true><<<(NNODES * 32 + 255) / 256, 256, 0, stream>>>(
        R0, rowptr, adj, nullptr, P1h, P1l, nullptr);
    gemm_mfma_kernel<8, 4, 4, 2, false, false, true, false, true, false, 3>
        <<<dim3(GB2, 2), 256, 0, stream>>>(nullptr, P1h, P1l, whi[2], wlo[2], g1_b1, nullptr, R0,
                                           nullptr, nullptr, stats, NNODES, 128, 256);
    bnfinal_kernel<<<1, 256, 0, stream>>>(stats, g1_ga, g1_be, scsh, 256, 1.0f / NNODES);
    gemm_mfma_kernel<8, 8, 8, 2, true, true, false, false, false, true, 3>
        <<<dim3(GB2, 2), 256, 0, stream>>>(R0, nullptr, nullptr, whi[3], wlo[3], g1_b2, scsh,
                                           nullptr, P2h, P2l, nullptr, NNODES, 256, 256);

    // ================= Layer 2 (256 -> 128 -> 128), REORDERED =================
    gemm_mfma_kernel<8, 8, 8, 2, false, false, false, false, true, false, 3>
        <<<GB2, 256, 0, stream>>>(nullptr, P2h, P2l, whi[4], wlo[4], nullptr, nullptr, R0, nullptr,
                                  nullptr, nullptr, NNODES, 256, 128);
    gather_kernel<128, 4, 128, false><<<(NNODES * 32 + 255) / 256, 256, 0, stream>>>(
        R0, rowptr, adj, R1, nullptr, nullptr, g2_b1);
    bnstats_kernel<128><<<256, 256, 0, stream>>>(R1, stats);
    bnfinal_kernel<<<1, 256, 0, stream>>>(stats, g2_ga, g2_be, scsh, 128, 1.0f / NNODES);
    gemm_mfma_kernel<8, 4, 4, 2, true, true, false, false, false, false, 3>
        <<<GB2, 256, 0, stream>>>(R1, nullptr, nullptr, whi[5], wlo[5], g2_b2, scsh, R0, nullptr,
                                  nullptr, nullptr, NNODES, 128, 128);

    // ================= pool + FC head (all MFMA, all ASPLIT) =================
    pool_seg_kernel<true><<<NGRAPHS, 128, 0, stream>>>(R0, gstart, nullptr, GPh, GPl);

    // fc0: relu(g @ fc0_w + fc0_b) -> gh planes. grid (2048/128, 1024/(8*16)) = (16, 8).
    gemm_mfma_kernel<8, 4, 4, 2, false, true, false, false, true, true, 3>
        <<<dim3(NGRAPHS / 128, 8), 256, 0, stream>>>(nullptr, GPh, GPl, whi[6], wlo[6], fc0_b,
                                                     nullptr, nullptr, GHh, GHl, nullptr, NGRAPHS,
                                                     128, 1024);
    // fc1 split-K: 8 chunks of KTLOOP=4 over KTT=32 -> partials in R1, then reduce+bias.
    gemm_mfma_kernel<8, 4, 32, 2, false, false, false, true, true, false, 3>
        <<<dim3(NGRAPHS / 128, 1, 8), 256, 0, stream>>>(nullptr, GHh, GHl, whi[7], wlo[7], nullptr,
                                                        nullptr, R1, nullptr, nullptr, nullptr,
                                                        NGRAPHS, 1024, 128);
    splitk_reduce_kernel<<<(NGRAPHS * 128 / 4 + 255) / 256, 256, 0, stream>>>(R1, fc1_b,
                                                                              (float*)d_out);
}

// Round 11
// 1083.912 us; speedup vs baseline: 1.0716x; 1.0406x over previous
//
#include <hip/hip_runtime.h>

#define NNODES 100000
#define NEDGES 1600000
#define NGRAPHS 2048
#define BN_EPS 1e-5f

typedef __attribute__((ext_vector_type(8))) short bf16x8;
typedef __attribute__((ext_vector_type(4))) float f32x4;

// RNE float -> bf16 (as short bits)
__device__ __forceinline__ short f2bf(float x) {
    unsigned u = __float_as_uint(x);
    unsigned r = u + 0x7FFF + ((u >> 16) & 1);
    return (short)(r >> 16);
}
__device__ __forceinline__ float bf2f(short h) {
    return __uint_as_float(((unsigned)(unsigned short)h) << 16);
}

// ---------------- CSR build ----------------
// Single atomic pass with line-padded counters; fill pass atomic-free.
__global__ __launch_bounds__(256) void degoff_kernel(const int* __restrict__ dstA,
                                                     int* __restrict__ degp,
                                                     int* __restrict__ off) {
    int e = blockIdx.x * 256 + threadIdx.x;
    if (e < NEDGES) {
        int d = dstA[e];
        int c = atomicAdd(&degp[d << 4], 1);  // padded: 1 counter per 64B line
        off[e] = (d << 8) | c;                // max deg ~35 << 256 for uniform-random edges
    }
}

__global__ __launch_bounds__(256) void scan1_kernel(const int* __restrict__ degp,
                                                    int* __restrict__ partials) {
    int b = blockIdx.x;
    int i = b * 256 + threadIdx.x;
    int v = (i < NNODES) ? degp[i << 4] : 0;
    __shared__ int wsum[4];
#pragma unroll
    for (int off = 32; off; off >>= 1) v += __shfl_down(v, off);
    if ((threadIdx.x & 63) == 0) wsum[threadIdx.x >> 6] = v;
    __syncthreads();
    if (threadIdx.x == 0) partials[b] = wsum[0] + wsum[1] + wsum[2] + wsum[3];
}

__global__ __launch_bounds__(512) void scan2_kernel(int* __restrict__ partials, int nb) {
    __shared__ int s[512];
    int t = threadIdx.x;
    int v = (t < nb) ? partials[t] : 0;
    s[t] = v;
    __syncthreads();
    for (int off = 1; off < 512; off <<= 1) {
        int u = (t >= off) ? s[t - off] : 0;
        __syncthreads();
        s[t] += u;
        __syncthreads();
    }
    if (t < nb) partials[t] = s[t] - v;  // exclusive
}

__global__ __launch_bounds__(256) void scan3_kernel(const int* __restrict__ degp,
                                                    const int* __restrict__ partials,
                                                    int* __restrict__ rowptr,
                                                    const int* __restrict__ batch,
                                                    int* __restrict__ gstart) {
    int b = blockIdx.x;
    int t = threadIdx.x;
    int i = b * 256 + t;
    __shared__ int s[256];
    int v = (i < NNODES) ? degp[i << 4] : 0;
    s[t] = v;
    __syncthreads();
    for (int off = 1; off < 256; off <<= 1) {
        int u = (t >= off) ? s[t - off] : 0;
        __syncthreads();
        s[t] += u;
        __syncthreads();
    }
    if (i < NNODES) {
        int ex = partials[b] + s[t] - v;
        rowptr[i] = ex;
        int bb = batch[i];
        int bp = (i == 0) ? -1 : batch[i - 1];
        for (int g = bp + 1; g <= bb; ++g) gstart[g] = i;
        if (i == NNODES - 1)
            for (int g = bb + 1; g <= NGRAPHS; ++g) gstart[g] = NNODES;
    }
    if (b == 0 && t == 0) rowptr[NNODES] = NEDGES;
}

__global__ __launch_bounds__(256) void fill2_kernel(const int* __restrict__ srcA,
                                                    const int* __restrict__ rowptr,
                                                    const int* __restrict__ off,
                                                    int* __restrict__ adj) {
    int e = blockIdx.x * 256 + threadIdx.x;
    if (e < NEDGES) {
        int v = off[e];
        adj[rowptr[v >> 8] + (v & 255)] = srcA[e];  // no atomic; rowptr is L2-resident
    }
}

// ------- gather aggregation: agg[n] = x[n] + sum_{s in adj[n]} x[s] (+bias) -------
// TCC-FETCH bound (R10: request-halving on L0 changed nothing; all gathers ~123us at
// FETCH ~400MB => ~3.25 TB/s L2-miss traffic is the ceiling). Unroll 8 for latency.
// SPLIT epilogue emits hi/lo bf16 planes for the ASPLIT GEMM consumer.
template <int DIM, int CHUNK, int OSTRIDE, bool SPLIT>
__global__ __launch_bounds__(256) void gather_kernel(const float* __restrict__ x,
                                                     const int* __restrict__ rowptr,
                                                     const int* __restrict__ adj,
                                                     float* __restrict__ agg,
                                                     short* __restrict__ oh,
                                                     short* __restrict__ ol,
                                                     const float* __restrict__ bias) {
    constexpr int PE = DIM / CHUNK;
    constexpr int PEL = SPLIT ? (OSTRIDE / CHUNK) : PE;
    int gid = blockIdx.x * 256 + threadIdx.x;
    if (gid >= NNODES * PEL) return;
    int node = gid / PEL;
    int c = gid - node * PEL;
    if constexpr (SPLIT) {
        if (c >= PE) {  // zero-pad columns [DIM, OSTRIDE)
            size_t o = (size_t)node * OSTRIDE + c * CHUNK;
            if constexpr (CHUNK == 4) {
                short4 z;
                z.x = z.y = z.z = z.w = 0;
                *(short4*)&oh[o] = z;
                *(short4*)&ol[o] = z;
            } else {
                short2 z;
                z.x = z.y = 0;
                *(short2*)&oh[o] = z;
                *(short2*)&ol[o] = z;
            }
            return;
        }
    }
    const int beg = rowptr[node];
    const int end = rowptr[node + 1];
    if constexpr (CHUNK == 4) {
        const float4* xp = (const float4*)x;
        float4 acc = xp[(size_t)node * PE + c];
        float4 acc1 = make_float4(0.f, 0.f, 0.f, 0.f);
        int i = beg;
        for (; i + 8 <= end; i += 8) {
            int s0 = adj[i + 0], s1 = adj[i + 1], s2 = adj[i + 2], s3 = adj[i + 3];
            int s4 = adj[i + 4], s5 = adj[i + 5], s6 = adj[i + 6], s7 = adj[i + 7];
            float4 v0 = xp[(size_t)s0 * PE + c];
            float4 v1 = xp[(size_t)s1 * PE + c];
            float4 v2 = xp[(size_t)s2 * PE + c];
            float4 v3 = xp[(size_t)s3 * PE + c];
            float4 v4 = xp[(size_t)s4 * PE + c];
            float4 v5 = xp[(size_t)s5 * PE + c];
            float4 v6 = xp[(size_t)s6 * PE + c];
            float4 v7 = xp[(size_t)s7 * PE + c];
            acc.x += v0.x + v1.x; acc.y += v0.y + v1.y; acc.z += v0.z + v1.z; acc.w += v0.w + v1.w;
            acc1.x += v2.x + v3.x; acc1.y += v2.y + v3.y; acc1.z += v2.z + v3.z; acc1.w += v2.w + v3.w;
            acc.x += v4.x + v5.x; acc.y += v4.y + v5.y; acc.z += v4.z + v5.z; acc.w += v4.w + v5.w;
            acc1.x += v6.x + v7.x; acc1.y += v6.y + v7.y; acc1.z += v6.z + v7.z; acc1.w += v6.w + v7.w;
        }
        for (; i + 4 <= end; i += 4) {
            int s0 = adj[i + 0], s1 = adj[i + 1], s2 = adj[i + 2], s3 = adj[i + 3];
            float4 v0 = xp[(size_t)s0 * PE + c];
            float4 v1 = xp[(size_t)s1 * PE + c];
            float4 v2 = xp[(size_t)s2 * PE + c];
            float4 v3 = xp[(size_t)s3 * PE + c];
            acc.x += v0.x + v1.x; acc.y += v0.y + v1.y; acc.z += v0.z + v1.z; acc.w += v0.w + v1.w;
            acc1.x += v2.x + v3.x; acc1.y += v2.y + v3.y; acc1.z += v2.z + v3.z; acc1.w += v2.w + v3.w;
        }
        for (; i < end; ++i) {
            int s = adj[i];
            float4 v = xp[(size_t)s * PE + c];
            acc.x += v.x; acc.y += v.y; acc.z += v.z; acc.w += v.w;
        }
        acc.x += acc1.x; acc.y += acc1.y; acc.z += acc1.z; acc.w += acc1.w;
        if (bias) {
            float4 b = *(const float4*)&bias[c * 4];
            acc.x += b.x; acc.y += b.y; acc.z += b.z; acc.w += b.w;
        }
        if constexpr (SPLIT) {
            size_t o = (size_t)node * OSTRIDE + c * 4;
            short4 h4, l4;
            h4.x = f2bf(acc.x); l4.x = f2bf(acc.x - bf2f(h4.x));
            h4.y = f2bf(acc.y); l4.y = f2bf(acc.y - bf2f(h4.y));
            h4.z = f2bf(acc.z); l4.z = f2bf(acc.z - bf2f(h4.z));
            h4.w = f2bf(acc.w); l4.w = f2bf(acc.w - bf2f(h4.w));
            *(short4*)&oh[o] = h4;
            *(short4*)&ol[o] = l4;
        } else {
            *(float4*)&agg[(size_t)node * OSTRIDE + c * 4] = acc;
        }
    } else {
        const float2* xp = (const float2*)x;
        float2 acc = xp[(size_t)node * PE + c];
        float2 acc1 = make_float2(0.f, 0.f);
        int i = beg;
        for (; i + 8 <= end; i += 8) {
            int s0 = adj[i + 0], s1 = adj[i + 1], s2 = adj[i + 2], s3 = adj[i + 3];
            int s4 = adj[i + 4], s5 = adj[i + 5], s6 = adj[i + 6], s7 = adj[i + 7];
            float2 v0 = xp[(size_t)s0 * PE + c];
            float2 v1 = xp[(size_t)s1 * PE + c];
            float2 v2 = xp[(size_t)s2 * PE + c];
            float2 v3 = xp[(size_t)s3 * PE + c];
            float2 v4 = xp[(size_t)s4 * PE + c];
            float2 v5 = xp[(size_t)s5 * PE + c];
            float2 v6 = xp[(size_t)s6 * PE + c];
            float2 v7 = xp[(size_t)s7 * PE + c];
            acc.x += v0.x + v1.x; acc.y += v0.y + v1.y;
            acc1.x += v2.x + v3.x; acc1.y += v2.y + v3.y;
            acc.x += v4.x + v5.x; acc.y += v4.y + v5.y;
            acc1.x += v6.x + v7.x; acc1.y += v6.y + v7.y;
        }
        for (; i + 4 <= end; i += 4) {
            int s0 = adj[i + 0], s1 = adj[i + 1], s2 = adj[i + 2], s3 = adj[i + 3];
            float2 v0 = xp[(size_t)s0 * PE + c];
            float2 v1 = xp[(size_t)s1 * PE + c];
            float2 v2 = xp[(size_t)s2 * PE + c];
            float2 v3 = xp[(size_t)s3 * PE + c];
            acc.x += v0.x + v1.x; acc.y += v0.y + v1.y;
            acc1.x += v2.x + v3.x; acc1.y += v2.y + v3.y;
        }
        for (; i < end; ++i) {
            int s = adj[i];
            float2 v = xp[(size_t)s * PE + c];
            acc.x += v.x; acc.y += v.y;
        }
        acc.x += acc1.x; acc.y += acc1.y;
        if constexpr (SPLIT) {
            size_t o = (size_t)node * OSTRIDE + c * 2;
            short2 h2, l2;
            h2.x = f2bf(acc.x); l2.x = f2bf(acc.x - bf2f(h2.x));
            h2.y = f2bf(acc.y); l2.y = f2bf(acc.y - bf2f(h2.y));
            *(short2*)&oh[o] = h2;
            *(short2*)&ol[o] = l2;
        } else {
            *(float2*)&agg[(size_t)node * OSTRIDE + c * 2] = acc;
        }
    }
}

// ---------------- BN stats (standalone, used once for L2) ----------------
template <int N>
__global__ __launch_bounds__(256) void bnstats_kernel(const float* __restrict__ h,
                                                      float* __restrict__ sums) {
    constexpr int SHIFT = (N == 128) ? 7 : 8;
    int t = blockIdx.x * 256 + threadIdx.x;
    int col = t & (N - 1);
    int slice = t >> SHIFT;
    int stride = (gridDim.x * 256) >> SHIFT;
    float s = 0.f, s2 = 0.f;
    for (int r = slice; r < NNODES; r += stride) {
        float v = h[(size_t)r * N + col];
        s += v;
        s2 += v * v;
    }
    atomicAdd(&sums[col], s);
    atomicAdd(&sums[256 + col], s2);
}

// reads sums (sum@c, sumsq@256+c), writes scale@c / shift@256+c, then re-zeroes sums.
__global__ void bnfinal_kernel(float* __restrict__ sums, const float* __restrict__ gamma,
                               const float* __restrict__ beta, float* __restrict__ scsh, int N,
                               float invM) {
    int c = threadIdx.x;  // 256 threads always
    if (c < N) {
        float mean = sums[c] * invM;
        float var = sums[256 + c] * invM - mean * mean;
        float sc = gamma[c] * rsqrtf(var + BN_EPS);
        scsh[c] = sc;
        scsh[256 + c] = beta[c] - mean * sc;
    }
    sums[c] = 0.f;
    sums[256 + c] = 0.f;
}

// ---- W pre-pass (ALL weights in ONE dispatch): decompose W into hi/lo bf16 B-frags ----
// B-frag layout (mfma_f32_16x16x32_bf16): lane holds n=lane&15, k=(lane>>4)*8+j.
// Buffer index: ((nt*KT + kt)*64 + lane)*8 + j.
struct WDesc {
    const float* W;
    int Kw, N, KT, hioff, looff;
};
struct WDescs {
    WDesc d[8];
    int cum[9];
};
__global__ __launch_bounds__(256) void wprep_all_kernel(WDescs wd, short* __restrict__ wf) {
    int idx = blockIdx.x * 256 + threadIdx.x;
    if (idx >= wd.cum[8]) return;
    int s = 0;
#pragma unroll
    for (int i = 1; i < 8; ++i) s += (idx >= wd.cum[i]);
    int r = idx - wd.cum[s];
    const WDesc D = wd.d[s];
    int j = r & 7;
    int lane = (r >> 3) & 63;
    int t = r >> 9;  // nt*KT + kt
    int kt = t % D.KT;
    int nt = t / D.KT;
    int k = kt * 32 + ((lane >> 4) << 3) + j;
    int n = (nt << 4) + (lane & 15);
    float w = (k < D.Kw) ? D.W[(size_t)k * D.N + n] : 0.f;
    short hi = f2bf(w);
    wf[D.hioff + r] = hi;
    wf[D.looff + r] = f2bf(w - bf2f(hi));
}

// R11 B-hoist macros: named scalars (no arrays, no runtime indexing — rule #20 safe).
// LDB(i) loads the hi/lo B-fragment pair for n-tile i; MMNT(i) runs its 4*MROWS MFMAs
// in the SAME per-accumulator order as before => bit-identical results.
#define LDB(i)                                                                          \
    const bf16x8 bh##i = *(const bf16x8*)(Bh + (size_t)(i) * KTT * 512);                \
    const bf16x8 bl##i = *(const bf16x8*)(Bl + (size_t)(i) * KTT * 512);
#define MMNT(i)                                                                         \
    _Pragma("unroll") for (int m = 0; m < MROWS; ++m) {                                 \
        acc[m][(i)] =                                                                   \
            __builtin_amdgcn_mfma_f32_16x16x32_bf16(ahi[m], bh##i, acc[m][(i)], 0, 0, 0); \
        acc[m][(i)] =                                                                   \
            __builtin_amdgcn_mfma_f32_16x16x32_bf16(alo[m], bh##i, acc[m][(i)], 0, 0, 0); \
        acc[m][(i)] =                                                                   \
            __builtin_amdgcn_mfma_f32_16x16x32_bf16(ahi[m], bl##i, acc[m][(i)], 0, 0, 0); \
        acc[m][(i)] =                                                                   \
            __builtin_amdgcn_mfma_f32_16x16x32_bf16(alo[m], bl##i, acc[m][(i)], 0, 0, 0); \
    }

// ---------------- split-bf16 MFMA GEMM: C = op(A) @ W + bias ----------------
// LDS-free. Block = 4 waves; BM = 64*MROWS; NT=8 (grid.y splits N). MROWS=2 (R6/R7).
// R11: B-HOIST — R10 counters showed VGPR_Count=64 on the hot GEMM: the compiler was
// serializing each B-pair load right before its 4 MFMAs, exposing ~200cy L2 latency
// 8x per k-step. Fix: hoist the k-step's B-loads into named scalars (ASPLIT: all 16
// frags, peak ~160 regs < 170 cap; BN: 2 groups of 8, peak ~145), then the MFMA
// block. No cross-iteration carried state (R5 spill lesson). Bit-identical results.
template <int NT, int KTLOOP, int KTT, int MROWS, bool BNRELU_A, bool RELU_OUT, bool FUSE_STATS,
          bool SPLITK, bool ASPLIT, bool SPLIT_OUT, int MINW>
__global__ __launch_bounds__(256, MINW) void gemm_mfma_kernel(
    const float* __restrict__ A, const short* __restrict__ Ah, const short* __restrict__ Al,
    const short* __restrict__ whi, const short* __restrict__ wlo, const float* __restrict__ bias,
    const float* __restrict__ scsh, float* __restrict__ C, short* __restrict__ Ch,
    short* __restrict__ Cl, float* __restrict__ stats, int M, int Kst, int N) {
    __shared__ float sstat[512];
    const int tid = threadIdx.x;
    const int wave = tid >> 6;
    const int lane = tid & 63;
    const int quad = lane >> 4;
    const int l16 = lane & 15;
    const int mrow = blockIdx.x * (64 * MROWS) + wave * 16 + l16;
    const int ngrp = blockIdx.y * NT * 16;
    const size_t wgrp = (size_t)blockIdx.y * NT * KTT * 512;
    const int ktbeg = SPLITK ? blockIdx.z * KTLOOP : 0;
    float* Cb = SPLITK ? C + (size_t)blockIdx.z * M * N : C;

    if (FUSE_STATS) {
        sstat[tid] = 0.f;
        sstat[tid + 256] = 0.f;
        __syncthreads();
    }

    f32x4 acc[MROWS][NT] = {};

    auto kstep = [&](int kt) {
        const int kq = kt * 32 + quad * 8;
        bf16x8 ahi[MROWS], alo[MROWS];
        if constexpr (ASPLIT) {
#pragma unroll
            for (int m = 0; m < MROWS; ++m) {
                const size_t ro = (size_t)(mrow + m * 64) * Kst + kq;
                ahi[m] = *(const bf16x8*)(Ah + ro);
                alo[m] = *(const bf16x8*)(Al + ro);
            }
        } else {
            float sc[8], sh[8];
            if constexpr (BNRELU_A) {
                float4 sc0 = *(const float4*)&scsh[kq];
                float4 sc1 = *(const float4*)&scsh[kq + 4];
                float4 sh0 = *(const float4*)&scsh[256 + kq];
                float4 sh1 = *(const float4*)&scsh[256 + kq + 4];
                sc[0] = sc0.x; sc[1] = sc0.y; sc[2] = sc0.z; sc[3] = sc0.w;
                sc[4] = sc1.x; sc[5] = sc1.y; sc[6] = sc1.z; sc[7] = sc1.w;
                sh[0] = sh0.x; sh[1] = sh0.y; sh[2] = sh0.z; sh[3] = sh0.w;
                sh[4] = sh1.x; sh[5] = sh1.y; sh[6] = sh1.z; sh[7] = sh1.w;
            }
#pragma unroll
            for (int m = 0; m < MROWS; ++m) {
                const float* ap = A + (size_t)(mrow + m * 64) * Kst + kq;
                float4 x0 = *(const float4*)ap;
                float4 x1 = *(const float4*)(ap + 4);
                float a8[8] = {x0.x, x0.y, x0.z, x0.w, x1.x, x1.y, x1.z, x1.w};
                if constexpr (BNRELU_A) {
#pragma unroll
                    for (int i = 0; i < 8; ++i) a8[i] = fmaxf(a8[i] * sc[i] + sh[i], 0.f);
                }
#pragma unroll
                for (int i = 0; i < 8; ++i) {
                    short h = f2bf(a8[i]);
                    ahi[m][i] = h;
                    alo[m][i] = f2bf(a8[i] - bf2f(h));
                }
            }
        }
        const short* Bh = whi + wgrp + ((size_t)kt << 9) + ((size_t)lane << 3);
        const short* Bl = wlo + wgrp + ((size_t)kt << 9) + ((size_t)lane << 3);
        if constexpr (NT == 8) {
            if constexpr (ASPLIT) {
                // full hoist: 16 independent L2 loads in flight, then 32*MROWS MFMAs
                LDB(0) LDB(1) LDB(2) LDB(3) LDB(4) LDB(5) LDB(6) LDB(7)
                MMNT(0) MMNT(1) MMNT(2) MMNT(3) MMNT(4) MMNT(5) MMNT(6) MMNT(7)
            } else {
                // BN path: 2 groups of 8 frags (extra sc/sh/raw regs cap the budget)
                LDB(0) LDB(1) LDB(2) LDB(3)
                MMNT(0) MMNT(1) MMNT(2) MMNT(3)
                LDB(4) LDB(5) LDB(6) LDB(7)
                MMNT(4) MMNT(5) MMNT(6) MMNT(7)
            }
        } else {
#pragma unroll
            for (int nt = 0; nt < NT; ++nt) {
                bf16x8 bh = *(const bf16x8*)(Bh + (size_t)nt * KTT * 512);
                bf16x8 bl = *(const bf16x8*)(Bl + (size_t)nt * KTT * 512);
#pragma unroll
                for (int m = 0; m < MROWS; ++m) {
                    acc[m][nt] = __builtin_amdgcn_mfma_f32_16x16x32_bf16(ahi[m], bh, acc[m][nt], 0, 0, 0);
                    acc[m][nt] = __builtin_amdgcn_mfma_f32_16x16x32_bf16(alo[m], bh, acc[m][nt], 0, 0, 0);
                    acc[m][nt] = __builtin_amdgcn_mfma_f32_16x16x32_bf16(ahi[m], bl, acc[m][nt], 0, 0, 0);
                    acc[m][nt] = __builtin_amdgcn_mfma_f32_16x16x32_bf16(alo[m], bl, acc[m][nt], 0, 0, 0);
                }
            }
        }
    };

    if constexpr (ASPLIT) {
#pragma unroll 2
        for (int k = 0; k < KTLOOP; ++k) kstep(ktbeg + k);
    } else {
#pragma unroll 1
        for (int k = 0; k < KTLOOP; ++k) kstep(ktbeg + k);
    }

    // Epilogue. C/D frag: col = l16 (+16*nt), row = quad*4 + reg (m89-verified).
#pragma unroll
    for (int m = 0; m < MROWS; ++m) {
        const int mbase = blockIdx.x * (64 * MROWS) + m * 64 + wave * 16 + quad * 4;
#pragma unroll
        for (int nt = 0; nt < NT; ++nt) {
            int gn = ngrp + nt * 16 + l16;
            float bv = bias ? bias[gn] : 0.f;
            float s = 0.f, s2 = 0.f;
#pragma unroll
            for (int r = 0; r < 4; ++r) {
                int gm = mbase + r;
                float v = acc[m][nt][r] + bv;
                if (RELU_OUT) v = fmaxf(v, 0.f);
                if (gm < M) {
                    if constexpr (SPLIT_OUT) {
                        short h = f2bf(v);
                        Ch[(size_t)gm * N + gn] = h;
                        Cl[(size_t)gm * N + gn] = f2bf(v - bf2f(h));
                    } else {
                        Cb[(size_t)gm * N + gn] = v;
                    }
                    if (FUSE_STATS) {
                        s += v;
                        s2 += v * v;
                    }
                }
            }
            if (FUSE_STATS) {
                s += __shfl_xor(s, 16);
                s += __shfl_xor(s, 32);
                s2 += __shfl_xor(s2, 16);
                s2 += __shfl_xor(s2, 32);
                if (quad == 0) {
                    atomicAdd(&sstat[gn], s);
                    atomicAdd(&sstat[256 + gn], s2);
                }
            }
        }
    }
    if (FUSE_STATS) {
        __syncthreads();
        if (tid < N) {
            atomicAdd(&stats[tid], sstat[tid]);
            atomicAdd(&stats[256 + tid], sstat[256 + tid]);
        }
    }
}

#undef LDB
#undef MMNT

// ---- reduce 8 split-K partials + bias -> out (fc1: M=2048,N=128) ----
__global__ __launch_bounds__(256) void splitk_reduce_kernel(const float* __restrict__ part,
                                                            const float* __restrict__ bias,
                                                            float* __restrict__ out) {
    const int i4 = blockIdx.x * 256 + threadIdx.x;
    const int TOT4 = NGRAPHS * 128 / 4;  // 65536
    if (i4 >= TOT4) return;
    const float4* p = (const float4*)part;
    float4 acc = make_float4(0.f, 0.f, 0.f, 0.f);
#pragma unroll
    for (int c = 0; c < 8; ++c) {
        float4 v = p[(size_t)c * TOT4 + i4];
        acc.x += v.x;
        acc.y += v.y;
        acc.z += v.z;
        acc.w += v.w;
    }
    float4 b = ((const float4*)bias)[i4 & 31];
    acc.x += b.x;
    acc.y += b.y;
    acc.z += b.z;
    acc.w += b.w;
    ((float4*)out)[i4] = acc;
}

// ---- segmented pool over sorted batch; SPLIT emits hi/lo planes for fc0 ----
template <bool SPLIT>
__global__ __launch_bounds__(128) void pool_seg_kernel(const float* __restrict__ h,
                                                       const int* __restrict__ gstart,
                                                       float* __restrict__ g,
                                                       short* __restrict__ oh,
                                                       short* __restrict__ ol) {
    int gr = blockIdx.x;
    int t = threadIdx.x;
    int beg = gstart[gr];
    int end = gstart[gr + 1];
    float acc = 0.f;
    for (int r = beg; r < end; ++r) acc += h[(size_t)r * 128 + t];
    if constexpr (SPLIT) {
        short hh = f2bf(acc);
        oh[(size_t)gr * 128 + t] = hh;
        ol[(size_t)gr * 128 + t] = f2bf(acc - bf2f(hh));
    } else {
        g[(size_t)gr * 128 + t] = acc;
    }
}

extern "C" void kernel_launch(void* const* d_in, const int* in_sizes, int n_in, void* d_out,
                              int out_size, void* d_ws, size_t ws_size, hipStream_t stream) {
    const float* x = (const float*)d_in[0];
    const int* ei = (const int*)d_in[1];
    const int* batch = (const int*)d_in[2];
    const int* srcA = ei;
    const int* dstA = ei + NEDGES;

    const float* g0_w1 = (const float*)d_in[3];
    const float* g0_b1 = (const float*)d_in[4];
    const float* g0_ga = (const float*)d_in[5];
    const float* g0_be = (const float*)d_in[6];
    const float* g0_w2 = (const float*)d_in[7];
    const float* g0_b2 = (const float*)d_in[8];
    const float* g1_w1 = (const float*)d_in[9];
    const float* g1_b1 = (const float*)d_in[10];
    const float* g1_ga = (const float*)d_in[11];
    const float* g1_be = (const float*)d_in[12];
    const float* g1_w2 = (const float*)d_in[13];
    const float* g1_b2 = (const float*)d_in[14];
    const float* g2_w1 = (const float*)d_in[15];
    const float* g2_b1 = (const float*)d_in[16];
    const float* g2_ga = (const float*)d_in[17];
    const float* g2_be = (const float*)d_in[18];
    const float* g2_w2 = (const float*)d_in[19];
    const float* g2_b2 = (const float*)d_in[20];
    const float* fc0_w = (const float*)d_in[21];
    const float* fc0_b = (const float*)d_in[22];
    const float* fc1_w = (const float*)d_in[23];
    const float* fc1_b = (const float*)d_in[24];

    // --- workspace layout ---
    float* ws = (float*)d_ws;
    const size_t BUF = (size_t)NNODES * 256;
    float* R0 = ws;
    float* R1 = R0 + BUF;  // also fc1 split-K partial buffer (8*2048*128 floats)
    float* stats = R1 + BUF;                            // 512
    float* scsh = stats + 512;                          // 512
    float* g = scsh + 512;                              // 2048*128 pooled
    float* gh = g + (size_t)NGRAPHS * 128;              // 2048*1024 fc hidden
    int* rowptr = (int*)(gh + (size_t)NGRAPHS * 1024);  // NNODES+1
    int* adj = rowptr + NNODES + 4;                     // NEDGES
    int* partials = adj + NEDGES;                       // 391
    int* gstart = partials + 512;                       // NGRAPHS+1
    short* wf = (short*)(gstart + 2052);                // W-fragment arena

    // CSR scratch overlays dead R0 (R0 first written by L0 gather, after fill2):
    int* degp = (int*)R0;           // NNODES*16 ints (padded counters, 1/line)
    int* off = degp + NNODES * 16;  // NEDGES packed (dst<<8)|slot

    short* whi[8];
    short* wlo[8];
    for (int i = 0; i < 6; ++i) {
        whi[i] = wf + (size_t)i * 131072;
        wlo[i] = whi[i] + 65536;
    }
    whi[6] = wf + 6 * 131072;
    wlo[6] = whi[6] + 131072;
    whi[7] = whi[6] + 262144;
    wlo[7] = whi[7] + 131072;

    // bf16 A-plane overlays (hi plane then lo plane, both stride = padded K):
    short* P0h = (short*)R0;  // L0 gather out, stride 96 (cols 66..95 zeroed)
    short* P0l = P0h + (size_t)NNODES * 96;
    short* P1h = (short*)R1;  // L1 gather out, stride 128
    short* P1l = P1h + (size_t)NNODES * 128;
    short* P2h = (short*)R1;  // L1b out, stride 256 (fills R1 exactly)
    short* P2l = P2h + (size_t)NNODES * 256;
    short* GPh = (short*)g;  // pool out planes, stride 128
    short* GPl = GPh + (size_t)NGRAPHS * 128;
    short* GHh = (short*)gh;  // fc0 out planes, stride 1024
    short* GHl = GHh + (size_t)NGRAPHS * 1024;

    const int GB2 = (NNODES + 127) / 128;  // 782 row-blocks (MROWS=2)
    const int NB = (NNODES + 255) / 256;   // 391 scan blocks
    const int EB = (NEDGES + 255) / 256;   // edge blocks

    // --- build CSR + graph bounds (single atomic pass, line-padded counters) ---
    hipMemsetAsync(degp, 0, (size_t)NNODES * 16 * sizeof(int), stream);
    hipMemsetAsync(stats, 0, 512 * sizeof(float), stream);  // bnfinal re-zeroes thereafter
    degoff_kernel<<<EB, 256, 0, stream>>>(dstA, degp, off);
    scan1_kernel<<<NB, 256, 0, stream>>>(degp, partials);
    scan2_kernel<<<1, 512, 0, stream>>>(partials, NB);
    scan3_kernel<<<NB, 256, 0, stream>>>(degp, partials, rowptr, batch, gstart);
    fill2_kernel<<<EB, 256, 0, stream>>>(srcA, rowptr, off, adj);

    // --- W-fragment pre-pass: one dispatch for all 8 weights ---
    {
        WDescs wd;
        const float* Wp[8] = {g0_w1, g0_w2, g1_w1, g1_w2, g2_w1, g2_w2, fc0_w, fc1_w};
        const int Kw[8] = {66, 128, 128, 256, 256, 128, 128, 1024};
        const int Nn[8] = {128, 128, 256, 256, 128, 128, 1024, 128};
        const int KT[8] = {3, 4, 4, 8, 8, 4, 4, 32};
        int cum = 0;
        wd.cum[0] = 0;
        for (int i = 0; i < 8; ++i) {
            wd.d[i].W = Wp[i];
            wd.d[i].Kw = Kw[i];
            wd.d[i].N = Nn[i];
            wd.d[i].KT = KT[i];
            wd.d[i].hioff = (int)(whi[i] - wf);
            wd.d[i].looff = (int)(wlo[i] - wf);
            cum += (Nn[i] >> 4) * KT[i] * 512;
            wd.cum[i + 1] = cum;
        }
        wprep_all_kernel<<<(wd.cum[8] + 255) / 256, 256, 0, stream>>>(wd, wf);
    }

    // ================= Layer 0 (66 -> 128 -> 128) =================
    gather_kernel<66, 2, 96, true><<<(NNODES * 48 + 255) / 256, 256, 0, stream>>>(
        x, rowptr, adj, nullptr, P0h, P0l, nullptr);
    gemm_mfma_kernel<8, 3, 3, 2, false, false, true, false, true, false, 3>
        <<<GB2, 256, 0, stream>>>(nullptr, P0h, P0l, whi[0], wlo[0], g0_b1, nullptr, R1, nullptr,
                                  nullptr, stats, NNODES, 96, 128);
    bnfinal_kernel<<<1, 256, 0, stream>>>(stats, g0_ga, g0_be, scsh, 128, 1.0f / NNODES);
    gemm_mfma_kernel<8, 4, 4, 2, true, true, false, false, false, false, 3>
        <<<GB2, 256, 0, stream>>>(R1, nullptr, nullptr, whi[1], wlo[1], g0_b2, scsh, R0, nullptr,
                                  nullptr, nullptr, NNODES, 128, 128);

    // ================= Layer 1 (128 -> 256 -> 256) =================
    gather_kernel<128, 4, 128, true><<<(NNODES * 32 + 255) / 256, 256, 0, stream>>>(
        R0, rowptr, adj, nullptr, P1h, P1l, nullptr);
    gemm_mfma_kernel<8, 4, 4, 2, false, false, true, false, true, false, 3>
        <<<dim3(GB2, 2), 256, 0, stream>>>(nullptr, P1h, P1l, whi[2], wlo[2], g1_b1, nullptr, R0,
                                           nullptr, nullptr, stats, NNODES, 128, 256);
    bnfinal_kernel<<<1, 256, 0, stream>>>(stats, g1_ga, g1_be, scsh, 256, 1.0f / NNODES);
    gemm_mfma_kernel<8, 8, 8, 2, true, true, false, false, false, true, 3>
        <<<dim3(GB2, 2), 256, 0, stream>>>(R0, nullptr, nullptr, whi[3], wlo[3], g1_b2, scsh,
                                           nullptr, P2h, P2l, nullptr, NNODES, 256, 256);

    // ================= Layer 2 (256 -> 128 -> 128), REORDERED =================
    gemm_mfma_kernel<8, 8, 8, 2, false, false, false, false, true, false, 3>
        <<<GB2, 256, 0, stream>>>(nullptr, P2h, P2l, whi[4], wlo[4], nullptr, nullptr, R0, nullptr,
                                  nullptr, nullptr, NNODES, 256, 128);
    gather_kernel<128, 4, 128, false><<<(NNODES * 32 + 255) / 256, 256, 0, stream>>>(
        R0, rowptr, adj, R1, nullptr, nullptr, g2_b1);
    bnstats_kernel<128><<<256, 256, 0, stream>>>(R1, stats);
    bnfinal_kernel<<<1, 256, 0, stream>>>(stats, g2_ga, g2_be, scsh, 128, 1.0f / NNODES);
    gemm_mfma_kernel<8, 4, 4, 2, true, true, false, false, false, false, 3>
        <<<GB2, 256, 0, stream>>>(R1, nullptr, nullptr, whi[5], wlo[5], g2_b2, scsh, R0, nullptr,
                                  nullptr, nullptr, NNODES, 128, 128);

    // ================= pool + FC head (all MFMA, all ASPLIT) =================
    pool_seg_kernel<true><<<NGRAPHS, 128, 0, stream>>>(R0, gstart, nullptr, GPh, GPl);

    // fc0: relu(g @ fc0_w + fc0_b) -> gh planes. grid (2048/128, 1024/(8*16)) = (16, 8).
    gemm_mfma_kernel<8, 4, 4, 2, false, true, false, false, true, true, 3>
        <<<dim3(NGRAPHS / 128, 8), 256, 0, stream>>>(nullptr, GPh, GPl, whi[6], wlo[6], fc0_b,
                                                     nullptr, nullptr, GHh, GHl, nullptr, NGRAPHS,
                                                     128, 1024);
    // fc1 split-K: 8 chunks of KTLOOP=4 over KTT=32 -> partials in R1, then reduce+bias.
    gemm_mfma_kernel<8, 4, 32, 2, false, false, false, true, true, false, 3>
        <<<dim3(NGRAPHS / 128, 1, 8), 256, 0, stream>>>(nullptr, GHh, GHl, whi[7], wlo[7], nullptr,
                                                        nullptr, R1, nullptr, nullptr, nullptr,
                                                        NGRAPHS, 1024, 128);
    splitk_reduce_kernel<<<(NGRAPHS * 128 / 4 + 255) / 256, 256, 0, stream>>>(R1, fc1_b,
                                                                              (float*)d_out);
}